// Round 16
// baseline (779.864 us; speedup 1.0000x reference)
//
#include <hip/hip_runtime.h>
#include <math.h>

#define TT 4
#define BB 16
#define CC 384
#define NS 256
#define NHD 8
#define HDD 48
#define PLANE 98304      /* CC*NS */
#define TSTR  1572864    /* BB*PLANE */
#define TOT   6291456    /* TT*TSTR */
#define CCSQ  147456     /* CC*CC */
#define PB    99840      /* padded batch plane: 260*384 u16 */
#define PPL   1597440    /* padded t-plane: 16*260*384 u16 */

// workspace float offsets (total (8*TOT+16)*4 = 201.3 MB)
#define OFF_XS   0L            /* xs u16 [t][b][n][c] -> oid fp32 (step8) */
#define OFF_Q    (1L*TOT)      /* qb fp32 -> Cq fp32 (2*TSTR, steps4) -> qtim u16; vtl u16 upper */
#define OFF_K    (2L*TOT)      /* k_pre fp32 n-major -> proj_pre */
#define OFF_V    (3L*TOT)      /* v_pre fp32 n-major */
#define OFF_OUTS (4L*TOT)      /* qspT+splT | ksp u16 at +7*PPL (steps3-6); amap u8 (step7+) */
#define OFF_KTS  (11L*TOT/2)   /* partials | wsp | timw (dead by step6) -> kt hi/mid/lo */
#define OFF_VT   (7L*TOT)      /* vth + vtm u16 planes */
#define OFF_CNT  (8L*TOT)      /* u32 spike counter */

#define NPART 6144             /* TSTR/256 blocks of k_tim_lif */

typedef __attribute__((ext_vector_type(8))) short short8;
typedef __attribute__((ext_vector_type(4))) float f32x4;

__device__ __forceinline__ ushort f2bf(float x) {   // RTNE fp32->bf16
    union { float f; unsigned u; } c; c.f = x;
    unsigned r = c.u + 0x7FFFu + ((c.u >> 16) & 1u);
    return (ushort)(r >> 16);
}
__device__ __forceinline__ float bf2f(ushort h) {
    union { unsigned u; float f; } c; c.u = ((unsigned)h) << 16;
    return c.f;
}

// ---------------- fused transpose + LIF: x [t][b][c][n] -> xs [t][b][n][c] bf16 spikes ----------------
__global__ __launch_bounds__(256) void k_lif_x_t(const float* __restrict__ x,
                                                 ushort* __restrict__ xs)
{
    int b = blockIdx.z, c0 = blockIdx.y*64, n0 = blockIdx.x*64;
    __shared__ ushort T[64][72];
    int tid = threadIdx.x;
    int row = tid >> 2;
    int col4 = tid & 3;

    float v[16];
    #pragma unroll
    for (int i = 0; i < 16; i++) v[i] = 0.f;

    for (int t = 0; t < TT; t++) {
        __syncthreads();
        #pragma unroll
        for (int rep = 0; rep < 4; rep++) {
            int j = col4 + rep*4;
            float4 xv = *(const float4*)&x[(long)t*TSTR + (long)b*PLANE + (long)(c0+row)*NS + n0 + j*4];
            #pragma unroll
            for (int jj = 0; jj < 4; jj++) {
                int idx = rep*4 + jj;
                float xt = ((const float*)&xv)[jj];
                float vv = v[idx];
                vv += (xt - vv)*0.5f;
                float s = (vv - 1.0f) >= 0.f ? 1.f : 0.f;
                T[j*4+jj][row] = (s != 0.f) ? (ushort)0x3F80 : (ushort)0;
                v[idx] = vv*(1.f - s);
            }
        }
        __syncthreads();
        #pragma unroll
        for (int rep = 0; rep < 2; rep++) {
            int nrow = tid >> 2;
            int cq = (tid & 3) + rep*4;
            *(uint4*)&xs[(long)t*TSTR + (long)b*PLANE + (long)(n0+nrow)*CC + c0 + cq*8]
                = *(uint4*)&T[nrow][cq*8];
        }
    }
}

// ---------------- zero the halo pad rows of qspT (4 t) and splT (3 planes) ----------------
__global__ __launch_bounds__(256) void k_zero_pads(unsigned* __restrict__ qspT_u32)
{
    int i = blockIdx.x*256 + threadIdx.x;
    int plane = i / 768, rem = i % 768;
    int r = rem / 192, cu = rem % 192;
    int row = (r < 2) ? r : (256 + r);
    qspT_u32[(long)plane*(PB/2) + row*192 + cu] = 0;
}

// ---------------- split wq/wk/wv into bf16 hi/mid/lo planes ----------------
__global__ __launch_bounds__(256) void k_wsplit(
    const float* __restrict__ wq, const float* __restrict__ wk, const float* __restrict__ wv,
    ushort* __restrict__ wsp)
{
    int i = blockIdx.x*256 + threadIdx.x;
    int which = i / CCSQ, r = i % CCSQ;
    const float* W = (which==0) ? wq : (which==1 ? wk : wv);
    float v = W[r];
    ushort hi = f2bf(v);  float r1 = v - bf2f(hi);
    ushort md = f2bf(r1); float r2 = r1 - bf2f(md);
    ushort lo = f2bf(r2);
    long b = (long)which*3*CCSQ;
    wsp[b + r] = hi; wsp[b + CCSQ + r] = md; wsp[b + 2L*CCSQ + r] = lo;
}

// ---------------- split tim conv weights, tap-major: timw[(pl*5+tap)][d][c] ----------------
__global__ __launch_bounds__(256) void k_wsplit_tim(const float* __restrict__ tw,
                                                    ushort* __restrict__ timw)
{
    int i = blockIdx.x*256 + threadIdx.x;
    const float* src = tw + (long)i*5;
    #pragma unroll
    for (int tap = 0; tap < 5; tap++) {
        float v = src[tap];
        ushort hi = f2bf(v);  float r1 = v - bf2f(hi);
        ushort md = f2bf(r1); float r2 = r1 - bf2f(md);
        ushort lo = f2bf(r2);
        timw[(long)(0*5 + tap)*CCSQ + i] = hi;
        timw[(long)(1*5 + tap)*CCSQ + i] = md;
        timw[(long)(2*5 + tap)*CCSQ + i] = lo;
    }
}

// ---------------- MFMA QKV GEMM v4: all outputs n-major [b][n][c] fp32 ----------------
__global__ __launch_bounds__(512) void k_gemm_qkv_mfma(
    const ushort* __restrict__ wsp,
    const float* __restrict__ kbn, const float* __restrict__ vbn,
    const ushort* __restrict__ xs,
    float* __restrict__ qo, float* __restrict__ ko, float* __restrict__ vo)
{
    int which = blockIdx.y >> 6;      // 0=q,1=k,2=v
    int tb    = blockIdx.y & 63;
    const ushort* X = xs + (long)tb*PLANE;
    const ushort* Wb = wsp + (long)which*3*CCSQ;
    int d0 = blockIdx.x*64;

    __shared__ ushort Ws[3][64][40];
    __shared__ ushort Xs[256][40];

    int tid = threadIdx.x, lane = tid & 63, w = tid >> 6;
    int q4 = lane >> 4, l16 = lane & 15;
    int dstrip = w & 3, nh = w >> 2;

    f32x4 acc[8];
    #pragma unroll
    for (int nt = 0; nt < 8; nt++) acc[nt] = (f32x4){0.f,0.f,0.f,0.f};

    for (int k0 = 0; k0 < CC; k0 += 32) {
        __syncthreads();
        for (int idx = tid; idx < 1792; idx += 512) {
            if (idx < 768) {
                int pl = idx >> 8, rem = idx & 255;
                int d = rem >> 2, c8 = rem & 3;
                *(uint4*)&Ws[pl][d][c8*8] =
                    *(const uint4*)(Wb + (long)pl*CCSQ + (long)(d0+d)*CC + k0 + c8*8);
            } else {
                int j = idx - 768;
                int n = j >> 2, c8 = j & 3;
                *(uint4*)&Xs[n][c8*8] = *(const uint4*)(X + (long)n*CC + k0 + c8*8);
            }
        }
        __syncthreads();

        short8 wh = *(short8*)&Ws[0][dstrip*16 + l16][q4*8];
        short8 wm = *(short8*)&Ws[1][dstrip*16 + l16][q4*8];
        short8 wl = *(short8*)&Ws[2][dstrip*16 + l16][q4*8];
        #pragma unroll
        for (int nt = 0; nt < 8; nt++) {
            short8 xr = *(short8*)&Xs[nh*128 + nt*16 + l16][q4*8];
            acc[nt] = __builtin_amdgcn_mfma_f32_16x16x32_bf16(xr, wh, acc[nt], 0, 0, 0);
            acc[nt] = __builtin_amdgcn_mfma_f32_16x16x32_bf16(xr, wm, acc[nt], 0, 0, 0);
            acc[nt] = __builtin_amdgcn_mfma_f32_16x16x32_bf16(xr, wl, acc[nt], 0, 0, 0);
        }
    }

    float* Y = ((which==0) ? qo : (which==1 ? ko : vo)) + (long)tb*PLANE;
    int d = d0 + dstrip*16 + l16;
    float inv = 1.f, mu = 0.f, be = 0.f;
    if (which != 0) {
        const float* bn = (which==1) ? kbn : vbn;
        float g = bn[d]; be = bn[CC+d]; mu = bn[2*CC+d]; float va = bn[3*CC+d];
        inv = g / sqrtf(va + 1e-5f);
    }
    #pragma unroll
    for (int nt = 0; nt < 8; nt++) {
        #pragma unroll
        for (int r = 0; r < 4; r++) {
            int n = nh*128 + nt*16 + q4*4 + r;
            float v = acc[nt][r];
            if (which != 0) v = inv*(v - mu) + be;
            Y[(long)n*CC + d] = v;
        }
    }
}

// ---------------- LIF: q->qspT padded bf16; k->ksp u16; v->vsp u16 + vout fp32 ----------------
__global__ __launch_bounds__(256) void k_lif_qkv(
    const float* __restrict__ qb, const float* __restrict__ kb, const float* __restrict__ vb,
    ushort* __restrict__ qspT, ushort* __restrict__ ksp, ushort* __restrict__ vsp,
    float* __restrict__ vout)
{
    int which = blockIdx.y;
    int i = blockIdx.x*256 + threadIdx.x;   // flat [b][n][c]
    const float* rbuf = (which==0) ? qb : (which==1 ? kb : vb);
    float vth  = (which==0) ? 0.05f : 1.0f;
    int b = i / PLANE;
    long qofs = (long)i + b*1536 + 768;     // padded [b][n+2][c] (q only)
    int c=0, n2=0, h=0, dd=0;
    if (which == 2) {
        c = i % CC; n2 = (i / CC) % NS;
        h = c / HDD; dd = c % HDD;
    }
    float v = 0.f;
    #pragma unroll
    for (int t = 0; t < TT; t++) {
        float xt = rbuf[t*TSTR + i];
        v += (xt - v)*0.5f;
        float s = (v - vth) >= 0.f ? 1.f : 0.f;
        ushort sb = (s != 0.f) ? (ushort)0x3F80 : (ushort)0;
        if (which == 0)      qspT[(long)t*PPL + qofs] = sb;
        else if (which == 1) ksp[(long)t*TSTR + i] = sb;
        else {
            vsp[(long)t*TSTR + i] = sb;
            vout[(((long)(t*BB+b)*NHD + h)*NS + n2)*HDD + dd] = s;
        }
        v *= (1.f - s);
    }
}

// ---------------- batched MFMA conv(q_t), t=0,1,2 ----------------
// t=0: epilogue emits s_1 spikes -> splT[0]; t=1,2: store raw conv fp32 -> cq[(t-1)].
// Same (c0, tap, plane) MFMA order as R14 -> bit-identical accQ.
__global__ __launch_bounds__(512) void k_tim_convq_mfma(
    const ushort* __restrict__ timw, const float* __restrict__ bias,
    const ushort* __restrict__ qspT,    // padded planes [t][16][260][384]
    ushort* __restrict__ s1out,         // splT plane 0 (padded)
    float* __restrict__ cq)             // [2][b][n][c] fp32
{
    int z = blockIdx.z;                 // t*16 + b
    int t = z >> 4, b = z & 15;
    int d0 = blockIdx.y*64, n0 = blockIdx.x*64;
    const ushort* qp = qspT + (long)t*PPL + (long)b*PB;

    __shared__ ushort Xs[68][40];

    int tid = threadIdx.x, lane = tid & 63, w = tid >> 6;   // 8 waves
    int q4 = lane >> 4, l16 = lane & 15;
    int dstrip = w >> 1, nh = w & 1;

    const ushort* wb = timw + (long)(d0 + dstrip*16 + l16)*CC;

    f32x4 accQ[2];
    accQ[0] = (f32x4){0.f,0.f,0.f,0.f};
    accQ[1] = (f32x4){0.f,0.f,0.f,0.f};

    for (int c0 = 0; c0 < CC; c0 += 32) {
        __syncthreads();
        for (int idx = tid; idx < 272; idx += 512) {
            int r = idx >> 2, c8 = idx & 3;
            *(uint4*)&Xs[r][c8*8] = *(const uint4*)(qp + (long)(n0 + r)*CC + c0 + c8*8);
        }
        __syncthreads();

        #pragma unroll
        for (int tap = 0; tap < 5; tap++) {
            short8 w0 = *(const short8*)(wb + (long)(0*5 + tap)*CCSQ + c0 + q4*8);
            short8 w1 = *(const short8*)(wb + (long)(1*5 + tap)*CCSQ + c0 + q4*8);
            short8 w2 = *(const short8*)(wb + (long)(2*5 + tap)*CCSQ + c0 + q4*8);
            #pragma unroll
            for (int nt = 0; nt < 2; nt++) {
                int row = nh*32 + nt*16 + l16 + tap;
                short8 aq = *(short8*)&Xs[row][q4*8];
                accQ[nt] = __builtin_amdgcn_mfma_f32_16x16x32_bf16(aq, w0, accQ[nt], 0, 0, 0);
                accQ[nt] = __builtin_amdgcn_mfma_f32_16x16x32_bf16(aq, w1, accQ[nt], 0, 0, 0);
                accQ[nt] = __builtin_amdgcn_mfma_f32_16x16x32_bf16(aq, w2, accQ[nt], 0, 0, 0);
            }
        }
    }

    int d = d0 + dstrip*16 + l16;
    if (t == 0) {
        ushort* so = s1out + (long)b*PB;
        float bv = bias[d];
        #pragma unroll
        for (int nt = 0; nt < 2; nt++) {
            #pragma unroll
            for (int r = 0; r < 4; r++) {
                int n = n0 + nh*32 + nt*16 + q4*4 + r;
                float c = accQ[nt][r] + bv;
                float s = (c*0.5f - 0.3f) >= 0.f ? 1.f : 0.f;
                so[(long)(n + 2)*CC + d] = (s != 0.f) ? (ushort)0x3F80 : (ushort)0;
            }
        }
    } else {
        float* co = cq + (long)(t-1)*TSTR + (long)b*PLANE;
        #pragma unroll
        for (int nt = 0; nt < 2; nt++) {
            #pragma unroll
            for (int r = 0; r < 4; r++) {
                int n = n0 + nh*32 + nt*16 + q4*4 + r;
                co[(long)n*CC + d] = accQ[nt][r];
            }
        }
    }
}

// ---------------- serial MFMA conv(s_{i-1}) + combine with Cq ----------------
// 768 blocks (d-tile 32) for latency hiding; epilogue spike(0.6*accS + 0.4*Cq + bias).
__global__ __launch_bounds__(256) void k_tim_convs_mfma(
    const ushort* __restrict__ timw, const float* __restrict__ bias,
    const ushort* __restrict__ sTp,     // s_{i-1} padded plane
    const float* __restrict__ cq,       // conv(q_{i-1}) fp32 [b][n][c]
    ushort* __restrict__ sTo)           // s_i padded plane
{
    int b = blockIdx.z, d0 = blockIdx.y*32, n0 = blockIdx.x*64;
    const ushort* sp = sTp + (long)b*PB;

    __shared__ ushort Xs[68][40];

    int tid = threadIdx.x, lane = tid & 63, w = tid >> 6;   // 4 waves
    int q4 = lane >> 4, l16 = lane & 15;
    int dstrip = w >> 1, nh = w & 1;

    const ushort* wb = timw + (long)(d0 + dstrip*16 + l16)*CC;

    f32x4 accS[2];
    accS[0] = (f32x4){0.f,0.f,0.f,0.f};
    accS[1] = (f32x4){0.f,0.f,0.f,0.f};

    for (int c0 = 0; c0 < CC; c0 += 32) {
        __syncthreads();
        for (int idx = tid; idx < 272; idx += 256) {
            int r = idx >> 2, c8 = idx & 3;
            *(uint4*)&Xs[r][c8*8] = *(const uint4*)(sp + (long)(n0 + r)*CC + c0 + c8*8);
        }
        __syncthreads();

        #pragma unroll
        for (int tap = 0; tap < 5; tap++) {
            short8 w0 = *(const short8*)(wb + (long)(0*5 + tap)*CCSQ + c0 + q4*8);
            short8 w1 = *(const short8*)(wb + (long)(1*5 + tap)*CCSQ + c0 + q4*8);
            short8 w2 = *(const short8*)(wb + (long)(2*5 + tap)*CCSQ + c0 + q4*8);
            #pragma unroll
            for (int nt = 0; nt < 2; nt++) {
                int row = nh*32 + nt*16 + l16 + tap;
                short8 as = *(short8*)&Xs[row][q4*8];
                accS[nt] = __builtin_amdgcn_mfma_f32_16x16x32_bf16(as, w0, accS[nt], 0, 0, 0);
                accS[nt] = __builtin_amdgcn_mfma_f32_16x16x32_bf16(as, w1, accS[nt], 0, 0, 0);
                accS[nt] = __builtin_amdgcn_mfma_f32_16x16x32_bf16(as, w2, accS[nt], 0, 0, 0);
            }
        }
    }

    ushort* so = sTo + (long)b*PB;
    const float* co = cq + (long)b*PLANE;
    int d = d0 + dstrip*16 + l16;
    float bv = bias[d];
    #pragma unroll
    for (int nt = 0; nt < 2; nt++) {
        #pragma unroll
        for (int r = 0; r < 4; r++) {
            int n = n0 + nh*32 + nt*16 + q4*4 + r;
            float conv = 0.6f*accS[nt][r] + 0.4f*co[(long)n*CC + d];
            float c = conv + bv;
            float s = (c*0.5f - 0.3f) >= 0.f ? 1.f : 0.f;
            so[(long)(n + 2)*CC + d] = (s != 0.f) ? (ushort)0x3F80 : (ushort)0;
        }
    }
}

// ---------------- TIM output LIF -> qtim [b][n][c] + counts ----------------
__global__ __launch_bounds__(256) void k_tim_lif(const ushort* __restrict__ qspT,
                                                 const ushort* __restrict__ splT,
                                                 ushort* __restrict__ qtim,
                                                 unsigned* __restrict__ partials)
{
    int i = blockIdx.x*256 + threadIdx.x;
    int b = i / PLANE;
    long po = (long)i + b*1536 + 768;
    float v = 0.f; unsigned c = 0;
    #pragma unroll
    for (int t = 0; t < TT; t++) {
        float val;
        if (t == 0) {
            val = bf2f(qspT[po]);
        } else {
            float sf = bf2f(splT[(long)(t-1)*PPL + po]);
            float qf = bf2f(qspT[(long)t*PPL + po]);
            val = sf*0.6f + qf*0.4f;
        }
        v += (val - v)*0.5f;
        float s = (v - 0.5f) >= 0.f ? 1.f : 0.f;
        qtim[(long)t*TSTR + i] = (s != 0.f) ? (ushort)0x3F80 : (ushort)0;
        c += (unsigned)s;
        v *= (1.f - s);
    }
    #pragma unroll
    for (int off = 32; off >= 1; off >>= 1) c += __shfl_down(c, off, 64);
    __shared__ unsigned wsum[4];
    if ((threadIdx.x & 63) == 0) wsum[threadIdx.x >> 6] = c;
    __syncthreads();
    if (threadIdx.x == 0)
        partials[blockIdx.x] = wsum[0] + wsum[1] + wsum[2] + wsum[3];
}

// ---------------- reduce NPART partials -> cnt ----------------
__global__ __launch_bounds__(256) void k_cnt_reduce(const unsigned* __restrict__ partials,
                                                    unsigned* __restrict__ cnt)
{
    unsigned c = 0;
    for (int i = threadIdx.x; i < NPART; i += 256) c += partials[i];
    #pragma unroll
    for (int off = 32; off >= 1; off >>= 1) c += __shfl_down(c, off, 64);
    __shared__ unsigned wsum[4];
    if ((threadIdx.x & 63) == 0) wsum[threadIdx.x >> 6] = c;
    __syncthreads();
    if (threadIdx.x == 0)
        cnt[0] = wsum[0] + wsum[1] + wsum[2] + wsum[3];
}

// ---------------- MFMA dst transform + bn_last ----------------
__global__ __launch_bounds__(256) void k_dst_mfma(
    const float* __restrict__ dw, const float* __restrict__ dbn,
    const ushort* __restrict__ ksp, const ushort* __restrict__ vsp,
    ushort* __restrict__ kth, ushort* __restrict__ ktm, ushort* __restrict__ ktl,
    ushort* __restrict__ vth, ushort* __restrict__ vtm, ushort* __restrict__ vtl)
{
    int isv = blockIdx.x;
    int tbh = blockIdx.y;
    int tb = tbh >> 3, h = tbh & 7;
    const ushort* src = (isv ? vsp : ksp) + (long)tb*PLANE + h*HDD;

    __shared__ ushort Ws[3][48][72];

    int tid = threadIdx.x, lane = tid & 63, w = tid >> 6;
    int q4 = lane >> 4, l16 = lane & 15;

    for (int idx = tid; idx < 1728; idx += 256) {
        int pl = idx / 576, rem = idx % 576;
        int e = rem / 12, cu = rem % 12;
        *(unsigned*)&Ws[pl][e][48 + cu*2] = 0;
    }
    for (int idx = tid; idx < 2304; idx += 256) {
        int e = idx / 48, d = idx % 48;
        float v = dw[idx];
        ushort hi = f2bf(v);  float r1 = v - bf2f(hi);
        ushort md = f2bf(r1); float r2 = r1 - bf2f(md);
        ushort lo = f2bf(r2);
        Ws[0][e][d] = hi; Ws[1][e][d] = md; Ws[2][e][d] = lo;
    }
    __syncthreads();

    f32x4 acc[3][4];
    #pragma unroll
    for (int es = 0; es < 3; es++)
        #pragma unroll
        for (int nt = 0; nt < 4; nt++) acc[es][nt] = (f32x4){0.f,0.f,0.f,0.f};

    #pragma unroll
    for (int k0 = 0; k0 < 64; k0 += 32) {
        short8 a[3][3];
        #pragma unroll
        for (int pl = 0; pl < 3; pl++)
            #pragma unroll
            for (int es = 0; es < 3; es++)
                a[pl][es] = *(short8*)&Ws[pl][es*16 + l16][k0 + q4*8];
        #pragma unroll
        for (int nt = 0; nt < 4; nt++) {
            int n = w*64 + nt*16 + l16;
            short8 xr = *(const short8*)(src + (long)n*CC + k0 + q4*8);
            #pragma unroll
            for (int es = 0; es < 3; es++) {
                acc[es][nt] = __builtin_amdgcn_mfma_f32_16x16x32_bf16(a[0][es], xr, acc[es][nt], 0, 0, 0);
                acc[es][nt] = __builtin_amdgcn_mfma_f32_16x16x32_bf16(a[1][es], xr, acc[es][nt], 0, 0, 0);
                acc[es][nt] = __builtin_amdgcn_mfma_f32_16x16x32_bf16(a[2][es], xr, acc[es][nt], 0, 0, 0);
            }
        }
    }

    #pragma unroll
    for (int es = 0; es < 3; es++) {
        #pragma unroll
        for (int r = 0; r < 4; r++) {
            int e = es*16 + q4*4 + r;
            float g = dbn[e], be = dbn[48+e], mu = dbn[96+e], va = dbn[144+e];
            float inv = g / sqrtf(va + 1e-5f);
            #pragma unroll
            for (int nt = 0; nt < 4; nt++) {
                int n = w*64 + nt*16 + l16;
                float val = inv*(acc[es][nt][r] - mu) + be;
                ushort hi = f2bf(val);  float r1 = val - bf2f(hi);
                ushort md = f2bf(r1);   float r2 = r1 - bf2f(md);
                ushort lo = f2bf(r2);
                if (isv) {
                    long gi = ((long)tbh*HDD + e)*NS + n;
                    vth[gi] = hi; vtm[gi] = md; vtl[gi] = lo;
                } else {
                    long gi = ((long)tbh*NS + n)*HDD + e;
                    kth[gi] = hi; ktm[gi] = md; ktl[gi] = lo;
                }
            }
        }
    }
}

// ---------------- MFMA attention: QK^T * c1 -> fused LIF(0.5) -> u8 map ----------------
__global__ __launch_bounds__(256) void k_attn_mfma(
    const ushort* __restrict__ qtim,
    const ushort* __restrict__ kth, const ushort* __restrict__ ktm, const ushort* __restrict__ ktl,
    const unsigned* __restrict__ cnt, unsigned char* __restrict__ amap)
{
    int bh = blockIdx.z;
    int b = bh >> 3, h = bh & 7;
    int nbase = blockIdx.y*64, mbase = blockIdx.x*64;

    __shared__ ushort Qs[64][72];
    __shared__ ushort Kh[64][72];
    __shared__ ushort Km[64][72];
    __shared__ ushort Kl[64][72];

    int tid  = threadIdx.x;
    int lane = tid & 63, w = tid >> 6;
    int q4 = lane >> 4, l16 = lane & 15;

    float mean = (float)(*cnt) / 6291456.0f;
    float c1 = fminf(1.0f / sqrtf(mean*48.0f + 1e-6f), 10.0f);

    {
        unsigned* z0 = (unsigned*)&Qs[0][0];
        unsigned* z1 = (unsigned*)&Kh[0][0];
        unsigned* z2 = (unsigned*)&Km[0][0];
        unsigned* z3 = (unsigned*)&Kl[0][0];
        for (int i2 = tid; i2 < 64*72/2; i2 += 256) {
            z0[i2] = 0; z1[i2] = 0; z2[i2] = 0; z3[i2] = 0;
        }
    }

    float vmem[4][4];
    #pragma unroll
    for (int a = 0; a < 4; a++)
        #pragma unroll
        for (int r = 0; r < 4; r++) vmem[a][r] = 0.f;

    for (int t = 0; t < TT; t++) {
        int tb = t*BB + b;
        __syncthreads();
        const ushort* qsrc = qtim + (long)tb*PLANE + (long)nbase*CC + h*HDD;
        for (int idx = tid; idx < 768; idx += 256) {
            int n = idx / 12, c4 = idx % 12;
            *(uint2*)&Qs[n][c4*4] = *(const uint2*)(qsrc + (long)n*CC + c4*4);
        }
        long kb0 = ((long)(tb*NHD + h)*NS + mbase)*HDD;
        const ushort* kbh = kth + kb0;
        const ushort* kbm = ktm + kb0;
        const ushort* kbl = ktl + kb0;
        for (int idx = tid; idx < 1536; idx += 256) {
            int e2 = idx << 1;
            int m = e2 / HDD, er = e2 % HDD;
            *(unsigned*)&Kh[m][er] = *(const unsigned*)(kbh + e2);
            *(unsigned*)&Km[m][er] = *(const unsigned*)(kbm + e2);
            *(unsigned*)&Kl[m][er] = *(const unsigned*)(kbl + e2);
        }
        __syncthreads();

        int nrow = w*16 + l16;
        f32x4 acc[4];
        #pragma unroll
        for (int mt = 0; mt < 4; mt++) acc[mt] = (f32x4){0.f, 0.f, 0.f, 0.f};

        #pragma unroll
        for (int ks = 0; ks < 2; ks++) {
            short8 a = *(short8*)&Qs[nrow][ks*32 + q4*8];
            #pragma unroll
            for (int mt = 0; mt < 4; mt++) {
                int mrow = mt*16 + l16;
                short8 b_h = *(short8*)&Kh[mrow][ks*32 + q4*8];
                short8 b_m = *(short8*)&Km[mrow][ks*32 + q4*8];
                short8 b_l = *(short8*)&Kl[mrow][ks*32 + q4*8];
                acc[mt] = __builtin_amdgcn_mfma_f32_16x16x32_bf16(a, b_h, acc[mt], 0, 0, 0);
                acc[mt] = __builtin_amdgcn_mfma_f32_16x16x32_bf16(a, b_m, acc[mt], 0, 0, 0);
                acc[mt] = __builtin_amdgcn_mfma_f32_16x16x32_bf16(a, b_l, acc[mt], 0, 0, 0);
            }
        }

        long abase0 = ((long)(tb*NHD + h)*NS)*NS;
        #pragma unroll
        for (int mt = 0; mt < 4; mt++) {
            int m = mbase + mt*16 + l16;
            #pragma unroll
            for (int r = 0; r < 4; r++) {
                int n = nbase + w*16 + q4*4 + r;
                float a = acc[mt][r]*c1;
                float v = vmem[mt][r];
                v += (a - v)*0.5f;
                float s = (v - 0.5f) >= 0.f ? 1.f : 0.f;
                amap[abase0 + (long)n*NS + m] = (unsigned char)s;
                vmem[mt][r] = v*(1.f - s);
            }
        }
    }
}

// ---------------- MFMA out = amap @ v_t + identity -> oid fp32 [tb][c][n] ----------------
__global__ __launch_bounds__(512) void k_outmm_mfma(
    const unsigned char* __restrict__ amap,
    const ushort* __restrict__ vth, const ushort* __restrict__ vtm, const ushort* __restrict__ vtl,
    const float* __restrict__ x, float* __restrict__ oid)
{
    int tbh = blockIdx.x;
    int tb = tbh >> 3, h = tbh & 7;
    int tid = threadIdx.x, lane = tid & 63, w = tid >> 6;
    int q4 = lane >> 4, l16 = lane & 15;
    int nbase = w*32;

    long vbase = (long)tbh*HDD*NS;

    f32x4 acc[2][3];
    #pragma unroll
    for (int nt = 0; nt < 2; nt++)
        #pragma unroll
        for (int et = 0; et < 3; et++) acc[nt][et] = (f32x4){0.f,0.f,0.f,0.f};

    for (int k0 = 0; k0 < NS; k0 += 32) {
        short8 a[2];
        #pragma unroll
        for (int nt = 0; nt < 2; nt++) {
            const unsigned char* arow = amap + ((long)tbh*NS + nbase + nt*16 + l16)*NS;
            uint2 u = *(const uint2*)(arow + k0 + q4*8);
            #pragma unroll
            for (int j = 0; j < 4; j++) {
                a[nt][j]   = ((u.x >> (8*j)) & 0xFFu) ? (short)0x3F80 : (short)0;
                a[nt][j+4] = ((u.y >> (8*j)) & 0xFFu) ? (short)0x3F80 : (short)0;
            }
        }
        #pragma unroll
        for (int et = 0; et < 3; et++) {
            long vo = vbase + (long)(et*16 + l16)*NS + k0 + q4*8;
            short8 bh = *(const short8*)(vth + vo);
            short8 bm = *(const short8*)(vtm + vo);
            short8 bl = *(const short8*)(vtl + vo);
            #pragma unroll
            for (int nt = 0; nt < 2; nt++) {
                acc[nt][et] = __builtin_amdgcn_mfma_f32_16x16x32_bf16(a[nt], bh, acc[nt][et], 0, 0, 0);
                acc[nt][et] = __builtin_amdgcn_mfma_f32_16x16x32_bf16(a[nt], bm, acc[nt][et], 0, 0, 0);
                acc[nt][et] = __builtin_amdgcn_mfma_f32_16x16x32_bf16(a[nt], bl, acc[nt][et], 0, 0, 0);
            }
        }
    }
    #pragma unroll
    for (int nt = 0; nt < 2; nt++) {
        #pragma unroll
        for (int et = 0; et < 3; et++) {
            int e = et*16 + l16;
            int n = nbase + nt*16 + q4*4;
            long base = (long)tb*PLANE + (long)(h*HDD + e)*NS + n;
            float4 xi = *(const float4*)(x + base);
            float4 o4;
            o4.x = acc[nt][et][0] + xi.x;
            o4.y = acc[nt][et][1] + xi.y;
            o4.z = acc[nt][et][2] + xi.z;
            o4.w = acc[nt][et][3] + xi.w;
            *(float4*)(oid + base) = o4;
        }
    }
}

// ---------------- proj GEMM + bias + BN (fp32, LDS) ----------------
__global__ __launch_bounds__(256) void k_gemm_proj(
    const float* __restrict__ W, const float* __restrict__ bias, const float* __restrict__ bn,
    const float* __restrict__ Xfull, float* __restrict__ Yfull)
{
    int tb = blockIdx.z;
    const float* X = Xfull + (long)tb*PLANE;
    float* Y = Yfull + (long)tb*PLANE;
    int d0 = blockIdx.y*64, n0 = blockIdx.x*64;

    __shared__ float As[16][68];
    __shared__ float Bs[16][68];
    int tid = threadIdx.x;
    int ty = tid >> 4, tx = tid & 15;
    float acc[4][4] = {};

    for (int k0 = 0; k0 < CC; k0 += 16) {
        {
            int d = tid >> 2, kq = (tid & 3)*4;
            float4 a4 = *(const float4*)&W[(long)(d0+d)*CC + k0 + kq];
            As[kq+0][d]=a4.x; As[kq+1][d]=a4.y; As[kq+2][d]=a4.z; As[kq+3][d]=a4.w;
        }
        {
            int k = tid >> 4, nq = (tid & 15)*4;
            *(float4*)&Bs[k][nq] = *(const float4*)&X[(long)(k0+k)*NS + n0 + nq];
        }
        __syncthreads();
        #pragma unroll
        for (int kk = 0; kk < 16; kk++) {
            float a0=As[kk][ty*4+0], a1=As[kk][ty*4+1], a2=As[kk][ty*4+2], a3=As[kk][ty*4+3];
            float b0=Bs[kk][tx*4+0], b1=Bs[kk][tx*4+1], b2=Bs[kk][tx*4+2], b3=Bs[kk][tx*4+3];
            acc[0][0]+=a0*b0; acc[0][1]+=a0*b1; acc[0][2]+=a0*b2; acc[0][3]+=a0*b3;
            acc[1][0]+=a1*b0; acc[1][1]+=a1*b1; acc[1][2]+=a1*b2; acc[1][3]+=a1*b3;
            acc[2][0]+=a2*b0; acc[2][1]+=a2*b1; acc[2][2]+=a2*b2; acc[2][3]+=a2*b3;
            acc[3][0]+=a3*b0; acc[3][1]+=a3*b1; acc[3][2]+=a3*b2; acc[3][3]+=a3*b3;
        }
        __syncthreads();
    }
    #pragma unroll
    for (int i = 0; i < 4; i++) {
        int d = d0 + ty*4 + i;
        float g = bn[d], be = bn[CC+d], mu = bn[2*CC+d], va = bn[3*CC+d];
        float inv = g / sqrtf(va + 1e-5f);
        float bv = bias[d];
        float4 o4;
        o4.x = inv*((acc[i][0]+bv) - mu) + be;
        o4.y = inv*((acc[i][1]+bv) - mu) + be;
        o4.z = inv*((acc[i][2]+bv) - mu) + be;
        o4.w = inv*((acc[i][3]+bv) - mu) + be;
        *(float4*)&Y[(long)d*NS + n0 + tx*4] = o4;
    }
}

// ---------------- final LIF (vth=1.0) -> d_out ----------------
__global__ __launch_bounds__(256) void k_final_lif(const float* __restrict__ pre,
                                                   float* __restrict__ out)
{
    int i = blockIdx.x*256 + threadIdx.x;
    float v = 0.f;
    #pragma unroll
    for (int t = 0; t < TT; t++) {
        float xt = pre[t*TSTR + i];
        v += (xt - v)*0.5f;
        float s = (v - 1.0f) >= 0.f ? 1.f : 0.f;
        out[t*TSTR + i] = s;
        v *= (1.f - s);
    }
}

extern "C" void kernel_launch(void* const* d_in, const int* in_sizes, int n_in,
                              void* d_out, int out_size, void* d_ws, size_t ws_size,
                              hipStream_t stream) {
    const float* x   = (const float*)d_in[0];
    const float* wq  = (const float*)d_in[1];
    const float* wk  = (const float*)d_in[2];
    const float* wv  = (const float*)d_in[3];
    const float* kbn = (const float*)d_in[4];
    const float* vbn = (const float*)d_in[5];
    const float* dw  = (const float*)d_in[6];
    const float* dbn = (const float*)d_in[7];
    const float* pw  = (const float*)d_in[8];
    const float* pb  = (const float*)d_in[9];
    const float* pbn = (const float*)d_in[10];
    const float* tw  = (const float*)d_in[11];
    const float* tbi = (const float*)d_in[12];

    float* out  = (float*)d_out;
    float* vout = out + TOT;

    float* ws   = (float*)d_ws;
    ushort* xs  = (ushort*)(ws + OFF_XS);
    float* oid  = ws + OFF_XS;
    float* qb   = ws + OFF_Q;      // q_pre fp32 (dead after step 3)
    float* cq   = ws + OFF_Q;      // Cq[2] fp32 (steps 4a-4c; overlaid by qtim at step 5)
    float* kb   = ws + OFF_K;
    float* vb   = ws + OFF_V;
    ushort* qtim = (ushort*)(ws + OFF_Q);          // Q lower half (step 5+)
    ushort* vtl  = (ushort*)(ws + OFF_Q) + TOT;    // Q upper half (step 6-8)
    ushort* qspT = (ushort*)(ws + OFF_OUTS);
    ushort* splT = qspT + 4L*PPL;
    ushort* ksp  = qspT + 7L*PPL;
    unsigned char* amap = (unsigned char*)(ws + OFF_OUTS);
    ushort* vsp = (ushort*)d_out;
    unsigned* partials = (unsigned*)(ws + OFF_KTS);
    ushort* wsp  = (ushort*)(ws + OFF_KTS) + 32768;
    ushort* timw = wsp + 9L*CCSQ;
    ushort* kth = (ushort*)(ws + OFF_KTS);
    ushort* ktm = kth + TOT;
    ushort* ktl = kth + 2L*TOT;
    ushort* vth = (ushort*)(ws + OFF_VT);
    ushort* vtm = vth + TOT;
    unsigned* cnt = (unsigned*)(ws + OFF_CNT);

    // 1. transpose-LIF -> xs [t][b][n][c]; split weights; zero halo pads
    k_lif_x_t<<<dim3(4, 6, 16), 256, 0, stream>>>(x, xs);
    k_wsplit<<<dim3(3*CCSQ/256), 256, 0, stream>>>(wq, wk, wv, wsp);
    k_wsplit_tim<<<dim3(CCSQ/256), 256, 0, stream>>>(tw, timw);
    k_zero_pads<<<dim3(336), 256, 0, stream>>>((unsigned*)qspT);
    // 2. q/k/v 1x1 convs via MFMA; all outputs n-major (+BN for k,v)
    k_gemm_qkv_mfma<<<dim3(6, 192), 512, 0, stream>>>(wsp, kbn, vbn, xs, qb, kb, vb);
    // 3. LIF: q->qspT padded; k->ksp u16; v->vsp u16 + vout
    k_lif_qkv<<<dim3(TSTR/256, 3), 256, 0, stream>>>(qb, kb, vb, qspT, ksp, vsp, vout);
    // 4a. batched conv(q_t) t=0,1,2: t=0 -> s_1 spikes (splT[0]); t=1,2 -> Cq fp32
    k_tim_convq_mfma<<<dim3(4, 6, 48), 512, 0, stream>>>(timw, tbi, qspT, splT, cq);
    // 4b/4c. serial s-conv steps (768 blocks each)
    for (int i = 2; i <= 3; i++) {
        k_tim_convs_mfma<<<dim3(4, 12, 16), 256, 0, stream>>>(
            timw, tbi,
            splT + (long)(i-2)*PPL,
            cq + (long)(i-2)*TSTR,
            splT + (long)(i-1)*PPL);
    }
    // 5. TIM output LIF -> qtim bf16 spikes + per-block counts
    k_tim_lif<<<dim3(NPART), 256, 0, stream>>>(qspT, splT, qtim, partials);
    k_cnt_reduce<<<dim3(1), 256, 0, stream>>>(partials, cnt);
    // 6. MFMA dst transform + bn_last
    k_dst_mfma<<<dim3(2, 512), 256, 0, stream>>>(dw, dbn, ksp, vsp, kth, ktm, ktl, vth, vtm, vtl);
    // 7. MFMA attention + fused LIF -> binary map
    k_attn_mfma<<<dim3(4, 4, 128), 256, 0, stream>>>(qtim, kth, ktm, ktl, cnt, amap);
    // 8. MFMA out = amap @ v_t + identity -> oid fp32
    k_outmm_mfma<<<dim3(512), 512, 0, stream>>>(amap, vth, vtm, vtl, x, oid);
    // 9. proj GEMM + bias + BN (fp32 LDS; proj_pre into kb buffer)
    k_gemm_proj<<<dim3(4, 6, 64), 256, 0, stream>>>(pw, pb, pbn, oid, kb);
    // 10. final LIF -> out
    k_final_lif<<<dim3(TSTR/256), 256, 0, stream>>>(kb, out);
}

// Round 17
// 638.170 us; speedup vs baseline: 1.2220x; 1.2220x over previous
//
#include <hip/hip_runtime.h>
#include <math.h>

#define TT 4
#define BB 16
#define CC 384
#define NS 256
#define NHD 8
#define HDD 48
#define PLANE 98304      /* CC*NS */
#define TSTR  1572864    /* BB*PLANE */
#define TOT   6291456    /* TT*TSTR */
#define CCSQ  147456     /* CC*CC */
#define PB    99840      /* padded batch plane: 260*384 u16 */
#define PPL   1597440    /* padded t-plane: 16*260*384 u16 */
#define WCHK  12288      /* CC*32: one fragment-major W chunk (u16) */

// workspace float offsets (total (8*TOT+16)*4 = 201.3 MB)
#define OFF_XS   0L            /* xs u16 [t][b][n][c] -> oid fp32 (step8) */
#define OFF_Q    (1L*TOT)      /* qb fp32 -> Cq fp32 (2*TSTR, steps4) -> qtim u16; vtl u16 upper */
#define OFF_K    (2L*TOT)      /* k_pre fp32 n-major -> proj_pre */
#define OFF_V    (3L*TOT)      /* v_pre fp32 n-major */
#define OFF_OUTS (4L*TOT)      /* qspT+splT | ksp u16 at +7*PPL (steps3-6); amap u8 (step7+) */
#define OFF_KTS  (11L*TOT/2)   /* partials | wsp | timw (dead by step6) -> kt hi/mid/lo */
#define OFF_VT   (7L*TOT)      /* vth + vtm u16 planes */
#define OFF_CNT  (8L*TOT)      /* u32 spike counter */

#define NPART 6144             /* TSTR/256 blocks of k_tim_lif */

typedef __attribute__((ext_vector_type(8))) short short8;
typedef __attribute__((ext_vector_type(4))) float f32x4;

__device__ __forceinline__ ushort f2bf(float x) {   // RTNE fp32->bf16
    union { float f; unsigned u; } c; c.f = x;
    unsigned r = c.u + 0x7FFFu + ((c.u >> 16) & 1u);
    return (ushort)(r >> 16);
}
__device__ __forceinline__ float bf2f(ushort h) {
    union { unsigned u; float f; } c; c.u = ((unsigned)h) << 16;
    return c.f;
}

// ---------------- fused transpose + LIF: x [t][b][c][n] -> xs [t][b][n][c] bf16 spikes ----------------
__global__ __launch_bounds__(256) void k_lif_x_t(const float* __restrict__ x,
                                                 ushort* __restrict__ xs)
{
    int b = blockIdx.z, c0 = blockIdx.y*64, n0 = blockIdx.x*64;
    __shared__ ushort T[64][72];
    int tid = threadIdx.x;
    int row = tid >> 2;
    int col4 = tid & 3;

    float v[16];
    #pragma unroll
    for (int i = 0; i < 16; i++) v[i] = 0.f;

    for (int t = 0; t < TT; t++) {
        __syncthreads();
        #pragma unroll
        for (int rep = 0; rep < 4; rep++) {
            int j = col4 + rep*4;
            float4 xv = *(const float4*)&x[(long)t*TSTR + (long)b*PLANE + (long)(c0+row)*NS + n0 + j*4];
            #pragma unroll
            for (int jj = 0; jj < 4; jj++) {
                int idx = rep*4 + jj;
                float xt = ((const float*)&xv)[jj];
                float vv = v[idx];
                vv += (xt - vv)*0.5f;
                float s = (vv - 1.0f) >= 0.f ? 1.f : 0.f;
                T[j*4+jj][row] = (s != 0.f) ? (ushort)0x3F80 : (ushort)0;
                v[idx] = vv*(1.f - s);
            }
        }
        __syncthreads();
        #pragma unroll
        for (int rep = 0; rep < 2; rep++) {
            int nrow = tid >> 2;
            int cq = (tid & 3) + rep*4;
            *(uint4*)&xs[(long)t*TSTR + (long)b*PLANE + (long)(n0+nrow)*CC + c0 + cq*8]
                = *(uint4*)&T[nrow][cq*8];
        }
    }
}

// ---------------- zero the halo pad rows of qspT (4 t) and splT (3 planes) ----------------
__global__ __launch_bounds__(256) void k_zero_pads(unsigned* __restrict__ qspT_u32)
{
    int i = blockIdx.x*256 + threadIdx.x;
    int plane = i / 768, rem = i % 768;
    int r = rem / 192, cu = rem % 192;
    int row = (r < 2) ? r : (256 + r);
    qspT_u32[(long)plane*(PB/2) + row*192 + cu] = 0;
}

// ---------------- split wq/wk/wv into bf16 hi/mid/lo planes ----------------
__global__ __launch_bounds__(256) void k_wsplit(
    const float* __restrict__ wq, const float* __restrict__ wk, const float* __restrict__ wv,
    ushort* __restrict__ wsp)
{
    int i = blockIdx.x*256 + threadIdx.x;
    int which = i / CCSQ, r = i % CCSQ;
    const float* W = (which==0) ? wq : (which==1 ? wk : wv);
    float v = W[r];
    ushort hi = f2bf(v);  float r1 = v - bf2f(hi);
    ushort md = f2bf(r1); float r2 = r1 - bf2f(md);
    ushort lo = f2bf(r2);
    long b = (long)which*3*CCSQ;
    wsp[b + r] = hi; wsp[b + CCSQ + r] = md; wsp[b + 2L*CCSQ + r] = lo;
}

// ---------------- split tim conv weights, FRAGMENT-MAJOR: timwP[pt][chunk][d][c32] ----------------
// One wave's B-fragment load (lane(q4,l16) -> d=base+l16, c=c0+q4*8) is 1024 contiguous
// bytes -> 8 fully-used cache lines (R15: 16 lines at 1/8 use -> 6.8 GB L2 traffic, 213 us).
__global__ __launch_bounds__(256) void k_wsplit_tim(const float* __restrict__ tw,
                                                    ushort* __restrict__ timw)
{
    int i = blockIdx.x*256 + threadIdx.x;   // [0, CCSQ) = (d,c), d-major
    int d = i / CC, c = i % CC;
    int ch = c >> 5, cw = c & 31;
    const float* src = tw + (long)i*5;
    #pragma unroll
    for (int tap = 0; tap < 5; tap++) {
        float v = src[tap];
        ushort hi = f2bf(v);  float r1 = v - bf2f(hi);
        ushort md = f2bf(r1); float r2 = r1 - bf2f(md);
        ushort lo = f2bf(r2);
        long o = (long)d*32 + cw;
        timw[((long)(0*5 + tap)*12 + ch)*WCHK + o] = hi;
        timw[((long)(1*5 + tap)*12 + ch)*WCHK + o] = md;
        timw[((long)(2*5 + tap)*12 + ch)*WCHK + o] = lo;
    }
}

// ---------------- MFMA QKV GEMM v4: all outputs n-major [b][n][c] fp32 ----------------
__global__ __launch_bounds__(512) void k_gemm_qkv_mfma(
    const ushort* __restrict__ wsp,
    const float* __restrict__ kbn, const float* __restrict__ vbn,
    const ushort* __restrict__ xs,
    float* __restrict__ qo, float* __restrict__ ko, float* __restrict__ vo)
{
    int which = blockIdx.y >> 6;      // 0=q,1=k,2=v
    int tb    = blockIdx.y & 63;
    const ushort* X = xs + (long)tb*PLANE;
    const ushort* Wb = wsp + (long)which*3*CCSQ;
    int d0 = blockIdx.x*64;

    __shared__ ushort Ws[3][64][40];
    __shared__ ushort Xs[256][40];

    int tid = threadIdx.x, lane = tid & 63, w = tid >> 6;
    int q4 = lane >> 4, l16 = lane & 15;
    int dstrip = w & 3, nh = w >> 2;

    f32x4 acc[8];
    #pragma unroll
    for (int nt = 0; nt < 8; nt++) acc[nt] = (f32x4){0.f,0.f,0.f,0.f};

    for (int k0 = 0; k0 < CC; k0 += 32) {
        __syncthreads();
        for (int idx = tid; idx < 1792; idx += 512) {
            if (idx < 768) {
                int pl = idx >> 8, rem = idx & 255;
                int d = rem >> 2, c8 = rem & 3;
                *(uint4*)&Ws[pl][d][c8*8] =
                    *(const uint4*)(Wb + (long)pl*CCSQ + (long)(d0+d)*CC + k0 + c8*8);
            } else {
                int j = idx - 768;
                int n = j >> 2, c8 = j & 3;
                *(uint4*)&Xs[n][c8*8] = *(const uint4*)(X + (long)n*CC + k0 + c8*8);
            }
        }
        __syncthreads();

        short8 wh = *(short8*)&Ws[0][dstrip*16 + l16][q4*8];
        short8 wm = *(short8*)&Ws[1][dstrip*16 + l16][q4*8];
        short8 wl = *(short8*)&Ws[2][dstrip*16 + l16][q4*8];
        #pragma unroll
        for (int nt = 0; nt < 8; nt++) {
            short8 xr = *(short8*)&Xs[nh*128 + nt*16 + l16][q4*8];
            acc[nt] = __builtin_amdgcn_mfma_f32_16x16x32_bf16(xr, wh, acc[nt], 0, 0, 0);
            acc[nt] = __builtin_amdgcn_mfma_f32_16x16x32_bf16(xr, wm, acc[nt], 0, 0, 0);
            acc[nt] = __builtin_amdgcn_mfma_f32_16x16x32_bf16(xr, wl, acc[nt], 0, 0, 0);
        }
    }

    float* Y = ((which==0) ? qo : (which==1 ? ko : vo)) + (long)tb*PLANE;
    int d = d0 + dstrip*16 + l16;
    float inv = 1.f, mu = 0.f, be = 0.f;
    if (which != 0) {
        const float* bn = (which==1) ? kbn : vbn;
        float g = bn[d]; be = bn[CC+d]; mu = bn[2*CC+d]; float va = bn[3*CC+d];
        inv = g / sqrtf(va + 1e-5f);
    }
    #pragma unroll
    for (int nt = 0; nt < 8; nt++) {
        #pragma unroll
        for (int r = 0; r < 4; r++) {
            int n = nh*128 + nt*16 + q4*4 + r;
            float v = acc[nt][r];
            if (which != 0) v = inv*(v - mu) + be;
            Y[(long)n*CC + d] = v;
        }
    }
}

// ---------------- LIF: q->qspT padded bf16; k->ksp u16; v->vsp u16 + vout fp32 ----------------
__global__ __launch_bounds__(256) void k_lif_qkv(
    const float* __restrict__ qb, const float* __restrict__ kb, const float* __restrict__ vb,
    ushort* __restrict__ qspT, ushort* __restrict__ ksp, ushort* __restrict__ vsp,
    float* __restrict__ vout)
{
    int which = blockIdx.y;
    int i = blockIdx.x*256 + threadIdx.x;   // flat [b][n][c]
    const float* rbuf = (which==0) ? qb : (which==1 ? kb : vb);
    float vth  = (which==0) ? 0.05f : 1.0f;
    int b = i / PLANE;
    long qofs = (long)i + b*1536 + 768;     // padded [b][n+2][c] (q only)
    int c=0, n2=0, h=0, dd=0;
    if (which == 2) {
        c = i % CC; n2 = (i / CC) % NS;
        h = c / HDD; dd = c % HDD;
    }
    float v = 0.f;
    #pragma unroll
    for (int t = 0; t < TT; t++) {
        float xt = rbuf[t*TSTR + i];
        v += (xt - v)*0.5f;
        float s = (v - vth) >= 0.f ? 1.f : 0.f;
        ushort sb = (s != 0.f) ? (ushort)0x3F80 : (ushort)0;
        if (which == 0)      qspT[(long)t*PPL + qofs] = sb;
        else if (which == 1) ksp[(long)t*TSTR + i] = sb;
        else {
            vsp[(long)t*TSTR + i] = sb;
            vout[(((long)(t*BB+b)*NHD + h)*NS + n2)*HDD + dd] = s;
        }
        v *= (1.f - s);
    }
}

// ---------------- batched MFMA conv(q_t), t=0,1,2 (fragment-major W) ----------------
__global__ __launch_bounds__(512) void k_tim_convq_mfma(
    const ushort* __restrict__ timw, const float* __restrict__ bias,
    const ushort* __restrict__ qspT,    // padded planes [t][16][260][384]
    ushort* __restrict__ s1out,         // splT plane 0 (padded)
    float* __restrict__ cq)             // [2][b][n][c] fp32
{
    int z = blockIdx.z;                 // t*16 + b
    int t = z >> 4, b = z & 15;
    int d0 = blockIdx.y*64, n0 = blockIdx.x*64;
    const ushort* qp = qspT + (long)t*PPL + (long)b*PB;

    __shared__ ushort Xs[68][40];

    int tid = threadIdx.x, lane = tid & 63, w = tid >> 6;   // 8 waves
    int q4 = lane >> 4, l16 = lane & 15;
    int dstrip = w >> 1, nh = w & 1;

    // fragment-major base: lane-contiguous within d-strip
    const ushort* wbase = timw + (long)(d0 + dstrip*16 + l16)*32 + q4*8;

    f32x4 accQ[2];
    accQ[0] = (f32x4){0.f,0.f,0.f,0.f};
    accQ[1] = (f32x4){0.f,0.f,0.f,0.f};

    for (int c0 = 0; c0 < CC; c0 += 32) {
        int ch = c0 >> 5;
        __syncthreads();
        for (int idx = tid; idx < 272; idx += 512) {
            int r = idx >> 2, c8 = idx & 3;
            *(uint4*)&Xs[r][c8*8] = *(const uint4*)(qp + (long)(n0 + r)*CC + c0 + c8*8);
        }
        __syncthreads();

        #pragma unroll
        for (int tap = 0; tap < 5; tap++) {
            short8 w0 = *(const short8*)(wbase + ((long)(0*5 + tap)*12 + ch)*WCHK);
            short8 w1 = *(const short8*)(wbase + ((long)(1*5 + tap)*12 + ch)*WCHK);
            short8 w2 = *(const short8*)(wbase + ((long)(2*5 + tap)*12 + ch)*WCHK);
            #pragma unroll
            for (int nt = 0; nt < 2; nt++) {
                int row = nh*32 + nt*16 + l16 + tap;
                short8 aq = *(short8*)&Xs[row][q4*8];
                accQ[nt] = __builtin_amdgcn_mfma_f32_16x16x32_bf16(aq, w0, accQ[nt], 0, 0, 0);
                accQ[nt] = __builtin_amdgcn_mfma_f32_16x16x32_bf16(aq, w1, accQ[nt], 0, 0, 0);
                accQ[nt] = __builtin_amdgcn_mfma_f32_16x16x32_bf16(aq, w2, accQ[nt], 0, 0, 0);
            }
        }
    }

    int d = d0 + dstrip*16 + l16;
    if (t == 0) {
        ushort* so = s1out + (long)b*PB;
        float bv = bias[d];
        #pragma unroll
        for (int nt = 0; nt < 2; nt++) {
            #pragma unroll
            for (int r = 0; r < 4; r++) {
                int n = n0 + nh*32 + nt*16 + q4*4 + r;
                float c = accQ[nt][r] + bv;
                float s = (c*0.5f - 0.3f) >= 0.f ? 1.f : 0.f;
                so[(long)(n + 2)*CC + d] = (s != 0.f) ? (ushort)0x3F80 : (ushort)0;
            }
        }
    } else {
        float* co = cq + (long)(t-1)*TSTR + (long)b*PLANE;
        #pragma unroll
        for (int nt = 0; nt < 2; nt++) {
            #pragma unroll
            for (int r = 0; r < 4; r++) {
                int n = n0 + nh*32 + nt*16 + q4*4 + r;
                co[(long)n*CC + d] = accQ[nt][r];
            }
        }
    }
}

// ---------------- serial MFMA conv(s_{i-1}) + combine with Cq (fragment-major W) ----------------
__global__ __launch_bounds__(256) void k_tim_convs_mfma(
    const ushort* __restrict__ timw, const float* __restrict__ bias,
    const ushort* __restrict__ sTp,     // s_{i-1} padded plane
    const float* __restrict__ cq,       // conv(q_{i-1}) fp32 [b][n][c]
    ushort* __restrict__ sTo)           // s_i padded plane
{
    int b = blockIdx.z, d0 = blockIdx.y*32, n0 = blockIdx.x*64;
    const ushort* sp = sTp + (long)b*PB;

    __shared__ ushort Xs[68][40];

    int tid = threadIdx.x, lane = tid & 63, w = tid >> 6;   // 4 waves
    int q4 = lane >> 4, l16 = lane & 15;
    int dstrip = w >> 1, nh = w & 1;

    const ushort* wbase = timw + (long)(d0 + dstrip*16 + l16)*32 + q4*8;

    f32x4 accS[2];
    accS[0] = (f32x4){0.f,0.f,0.f,0.f};
    accS[1] = (f32x4){0.f,0.f,0.f,0.f};

    for (int c0 = 0; c0 < CC; c0 += 32) {
        int ch = c0 >> 5;
        __syncthreads();
        for (int idx = tid; idx < 272; idx += 256) {
            int r = idx >> 2, c8 = idx & 3;
            *(uint4*)&Xs[r][c8*8] = *(const uint4*)(sp + (long)(n0 + r)*CC + c0 + c8*8);
        }
        __syncthreads();

        #pragma unroll
        for (int tap = 0; tap < 5; tap++) {
            short8 w0 = *(const short8*)(wbase + ((long)(0*5 + tap)*12 + ch)*WCHK);
            short8 w1 = *(const short8*)(wbase + ((long)(1*5 + tap)*12 + ch)*WCHK);
            short8 w2 = *(const short8*)(wbase + ((long)(2*5 + tap)*12 + ch)*WCHK);
            #pragma unroll
            for (int nt = 0; nt < 2; nt++) {
                int row = nh*32 + nt*16 + l16 + tap;
                short8 as = *(short8*)&Xs[row][q4*8];
                accS[nt] = __builtin_amdgcn_mfma_f32_16x16x32_bf16(as, w0, accS[nt], 0, 0, 0);
                accS[nt] = __builtin_amdgcn_mfma_f32_16x16x32_bf16(as, w1, accS[nt], 0, 0, 0);
                accS[nt] = __builtin_amdgcn_mfma_f32_16x16x32_bf16(as, w2, accS[nt], 0, 0, 0);
            }
        }
    }

    ushort* so = sTo + (long)b*PB;
    const float* co = cq + (long)b*PLANE;
    int d = d0 + dstrip*16 + l16;
    float bv = bias[d];
    #pragma unroll
    for (int nt = 0; nt < 2; nt++) {
        #pragma unroll
        for (int r = 0; r < 4; r++) {
            int n = n0 + nh*32 + nt*16 + q4*4 + r;
            float conv = 0.6f*accS[nt][r] + 0.4f*co[(long)n*CC + d];
            float c = conv + bv;
            float s = (c*0.5f - 0.3f) >= 0.f ? 1.f : 0.f;
            so[(long)(n + 2)*CC + d] = (s != 0.f) ? (ushort)0x3F80 : (ushort)0;
        }
    }
}

// ---------------- TIM output LIF -> qtim [b][n][c] + counts ----------------
__global__ __launch_bounds__(256) void k_tim_lif(const ushort* __restrict__ qspT,
                                                 const ushort* __restrict__ splT,
                                                 ushort* __restrict__ qtim,
                                                 unsigned* __restrict__ partials)
{
    int i = blockIdx.x*256 + threadIdx.x;
    int b = i / PLANE;
    long po = (long)i + b*1536 + 768;
    float v = 0.f; unsigned c = 0;
    #pragma unroll
    for (int t = 0; t < TT; t++) {
        float val;
        if (t == 0) {
            val = bf2f(qspT[po]);
        } else {
            float sf = bf2f(splT[(long)(t-1)*PPL + po]);
            float qf = bf2f(qspT[(long)t*PPL + po]);
            val = sf*0.6f + qf*0.4f;
        }
        v += (val - v)*0.5f;
        float s = (v - 0.5f) >= 0.f ? 1.f : 0.f;
        qtim[(long)t*TSTR + i] = (s != 0.f) ? (ushort)0x3F80 : (ushort)0;
        c += (unsigned)s;
        v *= (1.f - s);
    }
    #pragma unroll
    for (int off = 32; off >= 1; off >>= 1) c += __shfl_down(c, off, 64);
    __shared__ unsigned wsum[4];
    if ((threadIdx.x & 63) == 0) wsum[threadIdx.x >> 6] = c;
    __syncthreads();
    if (threadIdx.x == 0)
        partials[blockIdx.x] = wsum[0] + wsum[1] + wsum[2] + wsum[3];
}

// ---------------- reduce NPART partials -> cnt ----------------
__global__ __launch_bounds__(256) void k_cnt_reduce(const unsigned* __restrict__ partials,
                                                    unsigned* __restrict__ cnt)
{
    unsigned c = 0;
    for (int i = threadIdx.x; i < NPART; i += 256) c += partials[i];
    #pragma unroll
    for (int off = 32; off >= 1; off >>= 1) c += __shfl_down(c, off, 64);
    __shared__ unsigned wsum[4];
    if ((threadIdx.x & 63) == 0) wsum[threadIdx.x >> 6] = c;
    __syncthreads();
    if (threadIdx.x == 0)
        cnt[0] = wsum[0] + wsum[1] + wsum[2] + wsum[3];
}

// ---------------- MFMA dst transform + bn_last ----------------
__global__ __launch_bounds__(256) void k_dst_mfma(
    const float* __restrict__ dw, const float* __restrict__ dbn,
    const ushort* __restrict__ ksp, const ushort* __restrict__ vsp,
    ushort* __restrict__ kth, ushort* __restrict__ ktm, ushort* __restrict__ ktl,
    ushort* __restrict__ vth, ushort* __restrict__ vtm, ushort* __restrict__ vtl)
{
    int isv = blockIdx.x;
    int tbh = blockIdx.y;
    int tb = tbh >> 3, h = tbh & 7;
    const ushort* src = (isv ? vsp : ksp) + (long)tb*PLANE + h*HDD;

    __shared__ ushort Ws[3][48][72];

    int tid = threadIdx.x, lane = tid & 63, w = tid >> 6;
    int q4 = lane >> 4, l16 = lane & 15;

    for (int idx = tid; idx < 1728; idx += 256) {
        int pl = idx / 576, rem = idx % 576;
        int e = rem / 12, cu = rem % 12;
        *(unsigned*)&Ws[pl][e][48 + cu*2] = 0;
    }
    for (int idx = tid; idx < 2304; idx += 256) {
        int e = idx / 48, d = idx % 48;
        float v = dw[idx];
        ushort hi = f2bf(v);  float r1 = v - bf2f(hi);
        ushort md = f2bf(r1); float r2 = r1 - bf2f(md);
        ushort lo = f2bf(r2);
        Ws[0][e][d] = hi; Ws[1][e][d] = md; Ws[2][e][d] = lo;
    }
    __syncthreads();

    f32x4 acc[3][4];
    #pragma unroll
    for (int es = 0; es < 3; es++)
        #pragma unroll
        for (int nt = 0; nt < 4; nt++) acc[es][nt] = (f32x4){0.f,0.f,0.f,0.f};

    #pragma unroll
    for (int k0 = 0; k0 < 64; k0 += 32) {
        short8 a[3][3];
        #pragma unroll
        for (int pl = 0; pl < 3; pl++)
            #pragma unroll
            for (int es = 0; es < 3; es++)
                a[pl][es] = *(short8*)&Ws[pl][es*16 + l16][k0 + q4*8];
        #pragma unroll
        for (int nt = 0; nt < 4; nt++) {
            int n = w*64 + nt*16 + l16;
            short8 xr = *(const short8*)(src + (long)n*CC + k0 + q4*8);
            #pragma unroll
            for (int es = 0; es < 3; es++) {
                acc[es][nt] = __builtin_amdgcn_mfma_f32_16x16x32_bf16(a[0][es], xr, acc[es][nt], 0, 0, 0);
                acc[es][nt] = __builtin_amdgcn_mfma_f32_16x16x32_bf16(a[1][es], xr, acc[es][nt], 0, 0, 0);
                acc[es][nt] = __builtin_amdgcn_mfma_f32_16x16x32_bf16(a[2][es], xr, acc[es][nt], 0, 0, 0);
            }
        }
    }

    #pragma unroll
    for (int es = 0; es < 3; es++) {
        #pragma unroll
        for (int r = 0; r < 4; r++) {
            int e = es*16 + q4*4 + r;
            float g = dbn[e], be = dbn[48+e], mu = dbn[96+e], va = dbn[144+e];
            float inv = g / sqrtf(va + 1e-5f);
            #pragma unroll
            for (int nt = 0; nt < 4; nt++) {
                int n = w*64 + nt*16 + l16;
                float val = inv*(acc[es][nt][r] - mu) + be;
                ushort hi = f2bf(val);  float r1 = val - bf2f(hi);
                ushort md = f2bf(r1);   float r2 = r1 - bf2f(md);
                ushort lo = f2bf(r2);
                if (isv) {
                    long gi = ((long)tbh*HDD + e)*NS + n;
                    vth[gi] = hi; vtm[gi] = md; vtl[gi] = lo;
                } else {
                    long gi = ((long)tbh*NS + n)*HDD + e;
                    kth[gi] = hi; ktm[gi] = md; ktl[gi] = lo;
                }
            }
        }
    }
}

// ---------------- MFMA attention: QK^T * c1 -> fused LIF(0.5) -> u8 map ----------------
__global__ __launch_bounds__(256) void k_attn_mfma(
    const ushort* __restrict__ qtim,
    const ushort* __restrict__ kth, const ushort* __restrict__ ktm, const ushort* __restrict__ ktl,
    const unsigned* __restrict__ cnt, unsigned char* __restrict__ amap)
{
    int bh = blockIdx.z;
    int b = bh >> 3, h = bh & 7;
    int nbase = blockIdx.y*64, mbase = blockIdx.x*64;

    __shared__ ushort Qs[64][72];
    __shared__ ushort Kh[64][72];
    __shared__ ushort Km[64][72];
    __shared__ ushort Kl[64][72];

    int tid  = threadIdx.x;
    int lane = tid & 63, w = tid >> 6;
    int q4 = lane >> 4, l16 = lane & 15;

    float mean = (float)(*cnt) / 6291456.0f;
    float c1 = fminf(1.0f / sqrtf(mean*48.0f + 1e-6f), 10.0f);

    {
        unsigned* z0 = (unsigned*)&Qs[0][0];
        unsigned* z1 = (unsigned*)&Kh[0][0];
        unsigned* z2 = (unsigned*)&Km[0][0];
        unsigned* z3 = (unsigned*)&Kl[0][0];
        for (int i2 = tid; i2 < 64*72/2; i2 += 256) {
            z0[i2] = 0; z1[i2] = 0; z2[i2] = 0; z3[i2] = 0;
        }
    }

    float vmem[4][4];
    #pragma unroll
    for (int a = 0; a < 4; a++)
        #pragma unroll
        for (int r = 0; r < 4; r++) vmem[a][r] = 0.f;

    for (int t = 0; t < TT; t++) {
        int tb = t*BB + b;
        __syncthreads();
        const ushort* qsrc = qtim + (long)tb*PLANE + (long)nbase*CC + h*HDD;
        for (int idx = tid; idx < 768; idx += 256) {
            int n = idx / 12, c4 = idx % 12;
            *(uint2*)&Qs[n][c4*4] = *(const uint2*)(qsrc + (long)n*CC + c4*4);
        }
        long kb0 = ((long)(tb*NHD + h)*NS + mbase)*HDD;
        const ushort* kbh = kth + kb0;
        const ushort* kbm = ktm + kb0;
        const ushort* kbl = ktl + kb0;
        for (int idx = tid; idx < 1536; idx += 256) {
            int e2 = idx << 1;
            int m = e2 / HDD, er = e2 % HDD;
            *(unsigned*)&Kh[m][er] = *(const unsigned*)(kbh + e2);
            *(unsigned*)&Km[m][er] = *(const unsigned*)(kbm + e2);
            *(unsigned*)&Kl[m][er] = *(const unsigned*)(kbl + e2);
        }
        __syncthreads();

        int nrow = w*16 + l16;
        f32x4 acc[4];
        #pragma unroll
        for (int mt = 0; mt < 4; mt++) acc[mt] = (f32x4){0.f, 0.f, 0.f, 0.f};

        #pragma unroll
        for (int ks = 0; ks < 2; ks++) {
            short8 a = *(short8*)&Qs[nrow][ks*32 + q4*8];
            #pragma unroll
            for (int mt = 0; mt < 4; mt++) {
                int mrow = mt*16 + l16;
                short8 b_h = *(short8*)&Kh[mrow][ks*32 + q4*8];
                short8 b_m = *(short8*)&Km[mrow][ks*32 + q4*8];
                short8 b_l = *(short8*)&Kl[mrow][ks*32 + q4*8];
                acc[mt] = __builtin_amdgcn_mfma_f32_16x16x32_bf16(a, b_h, acc[mt], 0, 0, 0);
                acc[mt] = __builtin_amdgcn_mfma_f32_16x16x32_bf16(a, b_m, acc[mt], 0, 0, 0);
                acc[mt] = __builtin_amdgcn_mfma_f32_16x16x32_bf16(a, b_l, acc[mt], 0, 0, 0);
            }
        }

        long abase0 = ((long)(tb*NHD + h)*NS)*NS;
        #pragma unroll
        for (int mt = 0; mt < 4; mt++) {
            int m = mbase + mt*16 + l16;
            #pragma unroll
            for (int r = 0; r < 4; r++) {
                int n = nbase + w*16 + q4*4 + r;
                float a = acc[mt][r]*c1;
                float v = vmem[mt][r];
                v += (a - v)*0.5f;
                float s = (v - 0.5f) >= 0.f ? 1.f : 0.f;
                amap[abase0 + (long)n*NS + m] = (unsigned char)s;
                vmem[mt][r] = v*(1.f - s);
            }
        }
    }
}

// ---------------- MFMA out = amap @ v_t + identity -> oid fp32 [tb][c][n] ----------------
__global__ __launch_bounds__(512) void k_outmm_mfma(
    const unsigned char* __restrict__ amap,
    const ushort* __restrict__ vth, const ushort* __restrict__ vtm, const ushort* __restrict__ vtl,
    const float* __restrict__ x, float* __restrict__ oid)
{
    int tbh = blockIdx.x;
    int tb = tbh >> 3, h = tbh & 7;
    int tid = threadIdx.x, lane = tid & 63, w = tid >> 6;
    int q4 = lane >> 4, l16 = lane & 15;
    int nbase = w*32;

    long vbase = (long)tbh*HDD*NS;

    f32x4 acc[2][3];
    #pragma unroll
    for (int nt = 0; nt < 2; nt++)
        #pragma unroll
        for (int et = 0; et < 3; et++) acc[nt][et] = (f32x4){0.f,0.f,0.f,0.f};

    for (int k0 = 0; k0 < NS; k0 += 32) {
        short8 a[2];
        #pragma unroll
        for (int nt = 0; nt < 2; nt++) {
            const unsigned char* arow = amap + ((long)tbh*NS + nbase + nt*16 + l16)*NS;
            uint2 u = *(const uint2*)(arow + k0 + q4*8);
            #pragma unroll
            for (int j = 0; j < 4; j++) {
                a[nt][j]   = ((u.x >> (8*j)) & 0xFFu) ? (short)0x3F80 : (short)0;
                a[nt][j+4] = ((u.y >> (8*j)) & 0xFFu) ? (short)0x3F80 : (short)0;
            }
        }
        #pragma unroll
        for (int et = 0; et < 3; et++) {
            long vo = vbase + (long)(et*16 + l16)*NS + k0 + q4*8;
            short8 bh = *(const short8*)(vth + vo);
            short8 bm = *(const short8*)(vtm + vo);
            short8 bl = *(const short8*)(vtl + vo);
            #pragma unroll
            for (int nt = 0; nt < 2; nt++) {
                acc[nt][et] = __builtin_amdgcn_mfma_f32_16x16x32_bf16(a[nt], bh, acc[nt][et], 0, 0, 0);
                acc[nt][et] = __builtin_amdgcn_mfma_f32_16x16x32_bf16(a[nt], bm, acc[nt][et], 0, 0, 0);
                acc[nt][et] = __builtin_amdgcn_mfma_f32_16x16x32_bf16(a[nt], bl, acc[nt][et], 0, 0, 0);
            }
        }
    }
    #pragma unroll
    for (int nt = 0; nt < 2; nt++) {
        #pragma unroll
        for (int et = 0; et < 3; et++) {
            int e = et*16 + l16;
            int n = nbase + nt*16 + q4*4;
            long base = (long)tb*PLANE + (long)(h*HDD + e)*NS + n;
            float4 xi = *(const float4*)(x + base);
            float4 o4;
            o4.x = acc[nt][et][0] + xi.x;
            o4.y = acc[nt][et][1] + xi.y;
            o4.z = acc[nt][et][2] + xi.z;
            o4.w = acc[nt][et][3] + xi.w;
            *(float4*)(oid + base) = o4;
        }
    }
}

// ---------------- proj GEMM + bias + BN (fp32, LDS) ----------------
__global__ __launch_bounds__(256) void k_gemm_proj(
    const float* __restrict__ W, const float* __restrict__ bias, const float* __restrict__ bn,
    const float* __restrict__ Xfull, float* __restrict__ Yfull)
{
    int tb = blockIdx.z;
    const float* X = Xfull + (long)tb*PLANE;
    float* Y = Yfull + (long)tb*PLANE;
    int d0 = blockIdx.y*64, n0 = blockIdx.x*64;

    __shared__ float As[16][68];
    __shared__ float Bs[16][68];
    int tid = threadIdx.x;
    int ty = tid >> 4, tx = tid & 15;
    float acc[4][4] = {};

    for (int k0 = 0; k0 < CC; k0 += 16) {
        {
            int d = tid >> 2, kq = (tid & 3)*4;
            float4 a4 = *(const float4*)&W[(long)(d0+d)*CC + k0 + kq];
            As[kq+0][d]=a4.x; As[kq+1][d]=a4.y; As[kq+2][d]=a4.z; As[kq+3][d]=a4.w;
        }
        {
            int k = tid >> 4, nq = (tid & 15)*4;
            *(float4*)&Bs[k][nq] = *(const float4*)&X[(long)(k0+k)*NS + n0 + nq];
        }
        __syncthreads();
        #pragma unroll
        for (int kk = 0; kk < 16; kk++) {
            float a0=As[kk][ty*4+0], a1=As[kk][ty*4+1], a2=As[kk][ty*4+2], a3=As[kk][ty*4+3];
            float b0=Bs[kk][tx*4+0], b1=Bs[kk][tx*4+1], b2=Bs[kk][tx*4+2], b3=Bs[kk][tx*4+3];
            acc[0][0]+=a0*b0; acc[0][1]+=a0*b1; acc[0][2]+=a0*b2; acc[0][3]+=a0*b3;
            acc[1][0]+=a1*b0; acc[1][1]+=a1*b1; acc[1][2]+=a1*b2; acc[1][3]+=a1*b3;
            acc[2][0]+=a2*b0; acc[2][1]+=a2*b1; acc[2][2]+=a2*b2; acc[2][3]+=a2*b3;
            acc[3][0]+=a3*b0; acc[3][1]+=a3*b1; acc[3][2]+=a3*b2; acc[3][3]+=a3*b3;
        }
        __syncthreads();
    }
    #pragma unroll
    for (int i = 0; i < 4; i++) {
        int d = d0 + ty*4 + i;
        float g = bn[d], be = bn[CC+d], mu = bn[2*CC+d], va = bn[3*CC+d];
        float inv = g / sqrtf(va + 1e-5f);
        float bv = bias[d];
        float4 o4;
        o4.x = inv*((acc[i][0]+bv) - mu) + be;
        o4.y = inv*((acc[i][1]+bv) - mu) + be;
        o4.z = inv*((acc[i][2]+bv) - mu) + be;
        o4.w = inv*((acc[i][3]+bv) - mu) + be;
        *(float4*)&Y[(long)d*NS + n0 + tx*4] = o4;
    }
}

// ---------------- final LIF (vth=1.0) -> d_out ----------------
__global__ __launch_bounds__(256) void k_final_lif(const float* __restrict__ pre,
                                                   float* __restrict__ out)
{
    int i = blockIdx.x*256 + threadIdx.x;
    float v = 0.f;
    #pragma unroll
    for (int t = 0; t < TT; t++) {
        float xt = pre[t*TSTR + i];
        v += (xt - v)*0.5f;
        float s = (v - 1.0f) >= 0.f ? 1.f : 0.f;
        out[t*TSTR + i] = s;
        v *= (1.f - s);
    }
}

extern "C" void kernel_launch(void* const* d_in, const int* in_sizes, int n_in,
                              void* d_out, int out_size, void* d_ws, size_t ws_size,
                              hipStream_t stream) {
    const float* x   = (const float*)d_in[0];
    const float* wq  = (const float*)d_in[1];
    const float* wk  = (const float*)d_in[2];
    const float* wv  = (const float*)d_in[3];
    const float* kbn = (const float*)d_in[4];
    const float* vbn = (const float*)d_in[5];
    const float* dw  = (const float*)d_in[6];
    const float* dbn = (const float*)d_in[7];
    const float* pw  = (const float*)d_in[8];
    const float* pb  = (const float*)d_in[9];
    const float* pbn = (const float*)d_in[10];
    const float* tw  = (const float*)d_in[11];
    const float* tbi = (const float*)d_in[12];

    float* out  = (float*)d_out;
    float* vout = out + TOT;

    float* ws   = (float*)d_ws;
    ushort* xs  = (ushort*)(ws + OFF_XS);
    float* oid  = ws + OFF_XS;
    float* qb   = ws + OFF_Q;      // q_pre fp32 (dead after step 3)
    float* cq   = ws + OFF_Q;      // Cq[2] fp32 (steps 4a-4c; overlaid by qtim at step 5)
    float* kb   = ws + OFF_K;
    float* vb   = ws + OFF_V;
    ushort* qtim = (ushort*)(ws + OFF_Q);          // Q lower half (step 5+)
    ushort* vtl  = (ushort*)(ws + OFF_Q) + TOT;    // Q upper half (step 6-8)
    ushort* qspT = (ushort*)(ws + OFF_OUTS);
    ushort* splT = qspT + 4L*PPL;
    ushort* ksp  = qspT + 7L*PPL;
    unsigned char* amap = (unsigned char*)(ws + OFF_OUTS);
    ushort* vsp = (ushort*)d_out;
    unsigned* partials = (unsigned*)(ws + OFF_KTS);
    ushort* wsp  = (ushort*)(ws + OFF_KTS) + 32768;
    ushort* timw = wsp + 9L*CCSQ;
    ushort* kth = (ushort*)(ws + OFF_KTS);
    ushort* ktm = kth + TOT;
    ushort* ktl = kth + 2L*TOT;
    ushort* vth = (ushort*)(ws + OFF_VT);
    ushort* vtm = vth + TOT;
    unsigned* cnt = (unsigned*)(ws + OFF_CNT);

    // 1. transpose-LIF -> xs [t][b][n][c]; split weights (tim fragment-major); zero pads
    k_lif_x_t<<<dim3(4, 6, 16), 256, 0, stream>>>(x, xs);
    k_wsplit<<<dim3(3*CCSQ/256), 256, 0, stream>>>(wq, wk, wv, wsp);
    k_wsplit_tim<<<dim3(CCSQ/256), 256, 0, stream>>>(tw, timw);
    k_zero_pads<<<dim3(336), 256, 0, stream>>>((unsigned*)qspT);
    // 2. q/k/v 1x1 convs via MFMA; all outputs n-major (+BN for k,v)
    k_gemm_qkv_mfma<<<dim3(6, 192), 512, 0, stream>>>(wsp, kbn, vbn, xs, qb, kb, vb);
    // 3. LIF: q->qspT padded; k->ksp u16; v->vsp u16 + vout
    k_lif_qkv<<<dim3(TSTR/256, 3), 256, 0, stream>>>(qb, kb, vb, qspT, ksp, vsp, vout);
    // 4a. batched conv(q_t) t=0,1,2: t=0 -> s_1 spikes (splT[0]); t=1,2 -> Cq fp32
    k_tim_convq_mfma<<<dim3(4, 6, 48), 512, 0, stream>>>(timw, tbi, qspT, splT, cq);
    // 4b/4c. serial s-conv steps (768 blocks each)
    for (int i = 2; i <= 3; i++) {
        k_tim_convs_mfma<<<dim3(4, 12, 16), 256, 0, stream>>>(
            timw, tbi,
            splT + (long)(i-2)*PPL,
            cq + (long)(i-2)*TSTR,
            splT + (long)(i-1)*PPL);
    }
    // 5. TIM output LIF -> qtim bf16 spikes + per-block counts
    k_tim_lif<<<dim3(NPART), 256, 0, stream>>>(qspT, splT, qtim, partials);
    k_cnt_reduce<<<dim3(1), 256, 0, stream>>>(partials, cnt);
    // 6. MFMA dst transform + bn_last
    k_dst_mfma<<<dim3(2, 512), 256, 0, stream>>>(dw, dbn, ksp, vsp, kth, ktm, ktl, vth, vtm, vtl);
    // 7. MFMA attention + fused LIF -> binary map
    k_attn_mfma<<<dim3(4, 4, 128), 256, 0, stream>>>(qtim, kth, ktm, ktl, cnt, amap);
    // 8. MFMA out = amap @ v_t + identity -> oid fp32
    k_outmm_mfma<<<dim3(512), 512, 0, stream>>>(amap, vth, vtm, vtl, x, oid);
    // 9. proj GEMM + bias + BN (fp32 LDS; proj_pre into kb buffer)
    k_gemm_proj<<<dim3(4, 6, 64), 256, 0, stream>>>(pw, pb, pbn, oid, kb);
    // 10. final LIF -> out
    k_final_lif<<<dim3(TSTR/256), 256, 0, stream>>>(kb, out);
}

// Round 18
// 601.243 us; speedup vs baseline: 1.2971x; 1.0614x over previous
//
#include <hip/hip_runtime.h>
#include <math.h>

#define TT 4
#define BB 16
#define CC 384
#define NS 256
#define NHD 8
#define HDD 48
#define PLANE 98304      /* CC*NS */
#define TSTR  1572864    /* BB*PLANE */
#define TOT   6291456    /* TT*TSTR */
#define CCSQ  147456     /* CC*CC */
#define PB    99840      /* padded batch plane: 260*384 u16 */
#define PPL   1597440    /* padded t-plane: 16*260*384 u16 */
#define WCHK  12288      /* CC*32: one fragment-major W chunk (u16) */

// workspace float offsets (total (8*TOT+16)*4 = 201.3 MB)
#define OFF_XS   0L
#define OFF_Q    (1L*TOT)
#define OFF_K    (2L*TOT)
#define OFF_V    (3L*TOT)
#define OFF_OUTS (4L*TOT)
#define OFF_KTS  (11L*TOT/2)
#define OFF_VT   (7L*TOT)
#define OFF_CNT  (8L*TOT)

#define NPART 6144

typedef __attribute__((ext_vector_type(8))) short short8;
typedef __attribute__((ext_vector_type(4))) float f32x4;

__device__ __forceinline__ ushort f2bf(float x) {   // RTNE fp32->bf16
    union { float f; unsigned u; } c; c.f = x;
    unsigned r = c.u + 0x7FFFu + ((c.u >> 16) & 1u);
    return (ushort)(r >> 16);
}
__device__ __forceinline__ float bf2f(ushort h) {
    union { unsigned u; float f; } c; c.u = ((unsigned)h) << 16;
    return c.f;
}

// ---------------- fused transpose + LIF: x [t][b][c][n] -> xs [t][b][n][c] bf16 spikes ----------------
__global__ __launch_bounds__(256) void k_lif_x_t(const float* __restrict__ x,
                                                 ushort* __restrict__ xs)
{
    int b = blockIdx.z, c0 = blockIdx.y*64, n0 = blockIdx.x*64;
    __shared__ ushort T[64][72];
    int tid = threadIdx.x;
    int row = tid >> 2;
    int col4 = tid & 3;

    float v[16];
    #pragma unroll
    for (int i = 0; i < 16; i++) v[i] = 0.f;

    for (int t = 0; t < TT; t++) {
        __syncthreads();
        #pragma unroll
        for (int rep = 0; rep < 4; rep++) {
            int j = col4 + rep*4;
            float4 xv = *(const float4*)&x[(long)t*TSTR + (long)b*PLANE + (long)(c0+row)*NS + n0 + j*4];
            #pragma unroll
            for (int jj = 0; jj < 4; jj++) {
                int idx = rep*4 + jj;
                float xt = ((const float*)&xv)[jj];
                float vv = v[idx];
                vv += (xt - vv)*0.5f;
                float s = (vv - 1.0f) >= 0.f ? 1.f : 0.f;
                T[j*4+jj][row] = (s != 0.f) ? (ushort)0x3F80 : (ushort)0;
                v[idx] = vv*(1.f - s);
            }
        }
        __syncthreads();
        #pragma unroll
        for (int rep = 0; rep < 2; rep++) {
            int nrow = tid >> 2;
            int cq = (tid & 3) + rep*4;
            *(uint4*)&xs[(long)t*TSTR + (long)b*PLANE + (long)(n0+nrow)*CC + c0 + cq*8]
                = *(uint4*)&T[nrow][cq*8];
        }
    }
}

// ---------------- zero the halo pad rows of qspT (4 t) and splT (3 planes) ----------------
__global__ __launch_bounds__(256) void k_zero_pads(unsigned* __restrict__ qspT_u32)
{
    int i = blockIdx.x*256 + threadIdx.x;
    int plane = i / 768, rem = i % 768;
    int r = rem / 192, cu = rem % 192;
    int row = (r < 2) ? r : (256 + r);
    qspT_u32[(long)plane*(PB/2) + row*192 + cu] = 0;
}

// ---------------- split wq/wk/wv into bf16 hi/mid/lo planes ----------------
__global__ __launch_bounds__(256) void k_wsplit(
    const float* __restrict__ wq, const float* __restrict__ wk, const float* __restrict__ wv,
    ushort* __restrict__ wsp)
{
    int i = blockIdx.x*256 + threadIdx.x;
    int which = i / CCSQ, r = i % CCSQ;
    const float* W = (which==0) ? wq : (which==1 ? wk : wv);
    float v = W[r];
    ushort hi = f2bf(v);  float r1 = v - bf2f(hi);
    ushort md = f2bf(r1); float r2 = r1 - bf2f(md);
    ushort lo = f2bf(r2);
    long b = (long)which*3*CCSQ;
    wsp[b + r] = hi; wsp[b + CCSQ + r] = md; wsp[b + 2L*CCSQ + r] = lo;
}

// ---------------- split tim conv weights, FRAGMENT-MAJOR: timwP[pt][chunk][d][c32] ----------------
__global__ __launch_bounds__(256) void k_wsplit_tim(const float* __restrict__ tw,
                                                    ushort* __restrict__ timw)
{
    int i = blockIdx.x*256 + threadIdx.x;   // [0, CCSQ) = (d,c), d-major
    int d = i / CC, c = i % CC;
    int ch = c >> 5, cw = c & 31;
    const float* src = tw + (long)i*5;
    #pragma unroll
    for (int tap = 0; tap < 5; tap++) {
        float v = src[tap];
        ushort hi = f2bf(v);  float r1 = v - bf2f(hi);
        ushort md = f2bf(r1); float r2 = r1 - bf2f(md);
        ushort lo = f2bf(r2);
        long o = (long)d*32 + cw;
        timw[((long)(0*5 + tap)*12 + ch)*WCHK + o] = hi;
        timw[((long)(1*5 + tap)*12 + ch)*WCHK + o] = md;
        timw[((long)(2*5 + tap)*12 + ch)*WCHK + o] = lo;
    }
}

// ---------------- MFMA QKV GEMM v4: all outputs n-major [b][n][c] fp32 ----------------
__global__ __launch_bounds__(512) void k_gemm_qkv_mfma(
    const ushort* __restrict__ wsp,
    const float* __restrict__ kbn, const float* __restrict__ vbn,
    const ushort* __restrict__ xs,
    float* __restrict__ qo, float* __restrict__ ko, float* __restrict__ vo)
{
    int which = blockIdx.y >> 6;      // 0=q,1=k,2=v
    int tb    = blockIdx.y & 63;
    const ushort* X = xs + (long)tb*PLANE;
    const ushort* Wb = wsp + (long)which*3*CCSQ;
    int d0 = blockIdx.x*64;

    __shared__ ushort Ws[3][64][40];
    __shared__ ushort Xs[256][40];

    int tid = threadIdx.x, lane = tid & 63, w = tid >> 6;
    int q4 = lane >> 4, l16 = lane & 15;
    int dstrip = w & 3, nh = w >> 2;

    f32x4 acc[8];
    #pragma unroll
    for (int nt = 0; nt < 8; nt++) acc[nt] = (f32x4){0.f,0.f,0.f,0.f};

    for (int k0 = 0; k0 < CC; k0 += 32) {
        __syncthreads();
        for (int idx = tid; idx < 1792; idx += 512) {
            if (idx < 768) {
                int pl = idx >> 8, rem = idx & 255;
                int d = rem >> 2, c8 = rem & 3;
                *(uint4*)&Ws[pl][d][c8*8] =
                    *(const uint4*)(Wb + (long)pl*CCSQ + (long)(d0+d)*CC + k0 + c8*8);
            } else {
                int j = idx - 768;
                int n = j >> 2, c8 = j & 3;
                *(uint4*)&Xs[n][c8*8] = *(const uint4*)(X + (long)n*CC + k0 + c8*8);
            }
        }
        __syncthreads();

        short8 wh = *(short8*)&Ws[0][dstrip*16 + l16][q4*8];
        short8 wm = *(short8*)&Ws[1][dstrip*16 + l16][q4*8];
        short8 wl = *(short8*)&Ws[2][dstrip*16 + l16][q4*8];
        #pragma unroll
        for (int nt = 0; nt < 8; nt++) {
            short8 xr = *(short8*)&Xs[nh*128 + nt*16 + l16][q4*8];
            acc[nt] = __builtin_amdgcn_mfma_f32_16x16x32_bf16(xr, wh, acc[nt], 0, 0, 0);
            acc[nt] = __builtin_amdgcn_mfma_f32_16x16x32_bf16(xr, wm, acc[nt], 0, 0, 0);
            acc[nt] = __builtin_amdgcn_mfma_f32_16x16x32_bf16(xr, wl, acc[nt], 0, 0, 0);
        }
    }

    float* Y = ((which==0) ? qo : (which==1 ? ko : vo)) + (long)tb*PLANE;
    int d = d0 + dstrip*16 + l16;
    float inv = 1.f, mu = 0.f, be = 0.f;
    if (which != 0) {
        const float* bn = (which==1) ? kbn : vbn;
        float g = bn[d]; be = bn[CC+d]; mu = bn[2*CC+d]; float va = bn[3*CC+d];
        inv = g / sqrtf(va + 1e-5f);
    }
    #pragma unroll
    for (int nt = 0; nt < 8; nt++) {
        #pragma unroll
        for (int r = 0; r < 4; r++) {
            int n = nh*128 + nt*16 + q4*4 + r;
            float v = acc[nt][r];
            if (which != 0) v = inv*(v - mu) + be;
            Y[(long)n*CC + d] = v;
        }
    }
}

// ---------------- LIF: q->qspT padded bf16; k->ksp u16; v->vsp u16 + vout fp32 ----------------
__global__ __launch_bounds__(256) void k_lif_qkv(
    const float* __restrict__ qb, const float* __restrict__ kb, const float* __restrict__ vb,
    ushort* __restrict__ qspT, ushort* __restrict__ ksp, ushort* __restrict__ vsp,
    float* __restrict__ vout)
{
    int which = blockIdx.y;
    int i = blockIdx.x*256 + threadIdx.x;   // flat [b][n][c]
    const float* rbuf = (which==0) ? qb : (which==1 ? kb : vb);
    float vth  = (which==0) ? 0.05f : 1.0f;
    int b = i / PLANE;
    long qofs = (long)i + b*1536 + 768;     // padded [b][n+2][c] (q only)
    int c=0, n2=0, h=0, dd=0;
    if (which == 2) {
        c = i % CC; n2 = (i / CC) % NS;
        h = c / HDD; dd = c % HDD;
    }
    float v = 0.f;
    #pragma unroll
    for (int t = 0; t < TT; t++) {
        float xt = rbuf[t*TSTR + i];
        v += (xt - v)*0.5f;
        float s = (v - vth) >= 0.f ? 1.f : 0.f;
        ushort sb = (s != 0.f) ? (ushort)0x3F80 : (ushort)0;
        if (which == 0)      qspT[(long)t*PPL + qofs] = sb;
        else if (which == 1) ksp[(long)t*TSTR + i] = sb;
        else {
            vsp[(long)t*TSTR + i] = sb;
            vout[(((long)(t*BB+b)*NHD + h)*NS + n2)*HDD + dd] = s;
        }
        v *= (1.f - s);
    }
}

// ---------------- batched MFMA conv(q_t), t=0,1,2 — n-tile 128 for W reuse ----------------
// R16: n-tile 64 (2304 blocks) -> 1.66 GB L2 W traffic, 117us. n-tile 128 halves blocks,
// halves W traffic; 8 waves = 4 d-strips x 2 n-halves(64), 4 accumulators/wave.
__global__ __launch_bounds__(512) void k_tim_convq_mfma(
    const ushort* __restrict__ timw, const float* __restrict__ bias,
    const ushort* __restrict__ qspT,    // padded planes [t][16][260][384]
    ushort* __restrict__ s1out,         // splT plane 0 (padded)
    float* __restrict__ cq)             // [2][b][n][c] fp32
{
    int z = blockIdx.z;                 // t*16 + b
    int t = z >> 4, b = z & 15;
    int d0 = blockIdx.y*64, n0 = blockIdx.x*128;
    const ushort* qp = qspT + (long)t*PPL + (long)b*PB;

    __shared__ ushort Xs[132][40];      // halo rows n0-2 .. n0+129 (padded idx n0+r); 10.6 KB

    int tid = threadIdx.x, lane = tid & 63, w = tid >> 6;   // 8 waves
    int q4 = lane >> 4, l16 = lane & 15;
    int dstrip = w & 3, nh = w >> 2;    // wave: 16 d x 64 n

    const ushort* wbase = timw + (long)(d0 + dstrip*16 + l16)*32 + q4*8;

    f32x4 accQ[4];
    #pragma unroll
    for (int nt = 0; nt < 4; nt++) accQ[nt] = (f32x4){0.f,0.f,0.f,0.f};

    for (int c0 = 0; c0 < CC; c0 += 32) {
        int ch = c0 >> 5;
        __syncthreads();
        for (int idx = tid; idx < 528; idx += 512) {    // 132 rows x 4 uint4
            int r = idx >> 2, c8 = idx & 3;
            *(uint4*)&Xs[r][c8*8] = *(const uint4*)(qp + (long)(n0 + r)*CC + c0 + c8*8);
        }
        __syncthreads();

        #pragma unroll
        for (int tap = 0; tap < 5; tap++) {
            short8 w0 = *(const short8*)(wbase + ((long)(0*5 + tap)*12 + ch)*WCHK);
            short8 w1 = *(const short8*)(wbase + ((long)(1*5 + tap)*12 + ch)*WCHK);
            short8 w2 = *(const short8*)(wbase + ((long)(2*5 + tap)*12 + ch)*WCHK);
            #pragma unroll
            for (int nt = 0; nt < 4; nt++) {
                int row = nh*64 + nt*16 + l16 + tap;
                short8 aq = *(short8*)&Xs[row][q4*8];
                accQ[nt] = __builtin_amdgcn_mfma_f32_16x16x32_bf16(aq, w0, accQ[nt], 0, 0, 0);
                accQ[nt] = __builtin_amdgcn_mfma_f32_16x16x32_bf16(aq, w1, accQ[nt], 0, 0, 0);
                accQ[nt] = __builtin_amdgcn_mfma_f32_16x16x32_bf16(aq, w2, accQ[nt], 0, 0, 0);
            }
        }
    }

    int d = d0 + dstrip*16 + l16;
    if (t == 0) {
        ushort* so = s1out + (long)b*PB;
        float bv = bias[d];
        #pragma unroll
        for (int nt = 0; nt < 4; nt++) {
            #pragma unroll
            for (int r = 0; r < 4; r++) {
                int n = n0 + nh*64 + nt*16 + q4*4 + r;
                float c = accQ[nt][r] + bv;
                float s = (c*0.5f - 0.3f) >= 0.f ? 1.f : 0.f;
                so[(long)(n + 2)*CC + d] = (s != 0.f) ? (ushort)0x3F80 : (ushort)0;
            }
        }
    } else {
        float* co = cq + (long)(t-1)*TSTR + (long)b*PLANE;
        #pragma unroll
        for (int nt = 0; nt < 4; nt++) {
            #pragma unroll
            for (int r = 0; r < 4; r++) {
                int n = n0 + nh*64 + nt*16 + q4*4 + r;
                co[(long)n*CC + d] = accQ[nt][r];
            }
        }
    }
}

// ---------------- serial MFMA conv(s_{i-1}) + combine with Cq (fragment-major W) ----------------
__global__ __launch_bounds__(256) void k_tim_convs_mfma(
    const ushort* __restrict__ timw, const float* __restrict__ bias,
    const ushort* __restrict__ sTp,     // s_{i-1} padded plane
    const float* __restrict__ cq,       // conv(q_{i-1}) fp32 [b][n][c]
    ushort* __restrict__ sTo)           // s_i padded plane
{
    int b = blockIdx.z, d0 = blockIdx.y*32, n0 = blockIdx.x*64;
    const ushort* sp = sTp + (long)b*PB;

    __shared__ ushort Xs[68][40];

    int tid = threadIdx.x, lane = tid & 63, w = tid >> 6;   // 4 waves
    int q4 = lane >> 4, l16 = lane & 15;
    int dstrip = w >> 1, nh = w & 1;

    const ushort* wbase = timw + (long)(d0 + dstrip*16 + l16)*32 + q4*8;

    f32x4 accS[2];
    accS[0] = (f32x4){0.f,0.f,0.f,0.f};
    accS[1] = (f32x4){0.f,0.f,0.f,0.f};

    for (int c0 = 0; c0 < CC; c0 += 32) {
        int ch = c0 >> 5;
        __syncthreads();
        for (int idx = tid; idx < 272; idx += 256) {
            int r = idx >> 2, c8 = idx & 3;
            *(uint4*)&Xs[r][c8*8] = *(const uint4*)(sp + (long)(n0 + r)*CC + c0 + c8*8);
        }
        __syncthreads();

        #pragma unroll
        for (int tap = 0; tap < 5; tap++) {
            short8 w0 = *(const short8*)(wbase + ((long)(0*5 + tap)*12 + ch)*WCHK);
            short8 w1 = *(const short8*)(wbase + ((long)(1*5 + tap)*12 + ch)*WCHK);
            short8 w2 = *(const short8*)(wbase + ((long)(2*5 + tap)*12 + ch)*WCHK);
            #pragma unroll
            for (int nt = 0; nt < 2; nt++) {
                int row = nh*32 + nt*16 + l16 + tap;
                short8 as = *(short8*)&Xs[row][q4*8];
                accS[nt] = __builtin_amdgcn_mfma_f32_16x16x32_bf16(as, w0, accS[nt], 0, 0, 0);
                accS[nt] = __builtin_amdgcn_mfma_f32_16x16x32_bf16(as, w1, accS[nt], 0, 0, 0);
                accS[nt] = __builtin_amdgcn_mfma_f32_16x16x32_bf16(as, w2, accS[nt], 0, 0, 0);
            }
        }
    }

    ushort* so = sTo + (long)b*PB;
    const float* co = cq + (long)b*PLANE;
    int d = d0 + dstrip*16 + l16;
    float bv = bias[d];
    #pragma unroll
    for (int nt = 0; nt < 2; nt++) {
        #pragma unroll
        for (int r = 0; r < 4; r++) {
            int n = n0 + nh*32 + nt*16 + q4*4 + r;
            float conv = 0.6f*accS[nt][r] + 0.4f*co[(long)n*CC + d];
            float c = conv + bv;
            float s = (c*0.5f - 0.3f) >= 0.f ? 1.f : 0.f;
            so[(long)(n + 2)*CC + d] = (s != 0.f) ? (ushort)0x3F80 : (ushort)0;
        }
    }
}

// ---------------- TIM output LIF -> qtim [b][n][c] + counts ----------------
__global__ __launch_bounds__(256) void k_tim_lif(const ushort* __restrict__ qspT,
                                                 const ushort* __restrict__ splT,
                                                 ushort* __restrict__ qtim,
                                                 unsigned* __restrict__ partials)
{
    int i = blockIdx.x*256 + threadIdx.x;
    int b = i / PLANE;
    long po = (long)i + b*1536 + 768;
    float v = 0.f; unsigned c = 0;
    #pragma unroll
    for (int t = 0; t < TT; t++) {
        float val;
        if (t == 0) {
            val = bf2f(qspT[po]);
        } else {
            float sf = bf2f(splT[(long)(t-1)*PPL + po]);
            float qf = bf2f(qspT[(long)t*PPL + po]);
            val = sf*0.6f + qf*0.4f;
        }
        v += (val - v)*0.5f;
        float s = (v - 0.5f) >= 0.f ? 1.f : 0.f;
        qtim[(long)t*TSTR + i] = (s != 0.f) ? (ushort)0x3F80 : (ushort)0;
        c += (unsigned)s;
        v *= (1.f - s);
    }
    #pragma unroll
    for (int off = 32; off >= 1; off >>= 1) c += __shfl_down(c, off, 64);
    __shared__ unsigned wsum[4];
    if ((threadIdx.x & 63) == 0) wsum[threadIdx.x >> 6] = c;
    __syncthreads();
    if (threadIdx.x == 0)
        partials[blockIdx.x] = wsum[0] + wsum[1] + wsum[2] + wsum[3];
}

// ---------------- reduce NPART partials -> cnt ----------------
__global__ __launch_bounds__(256) void k_cnt_reduce(const unsigned* __restrict__ partials,
                                                    unsigned* __restrict__ cnt)
{
    unsigned c = 0;
    for (int i = threadIdx.x; i < NPART; i += 256) c += partials[i];
    #pragma unroll
    for (int off = 32; off >= 1; off >>= 1) c += __shfl_down(c, off, 64);
    __shared__ unsigned wsum[4];
    if ((threadIdx.x & 63) == 0) wsum[threadIdx.x >> 6] = c;
    __syncthreads();
    if (threadIdx.x == 0)
        cnt[0] = wsum[0] + wsum[1] + wsum[2] + wsum[3];
}

// ---------------- MFMA dst transform + bn_last ----------------
__global__ __launch_bounds__(256) void k_dst_mfma(
    const float* __restrict__ dw, const float* __restrict__ dbn,
    const ushort* __restrict__ ksp, const ushort* __restrict__ vsp,
    ushort* __restrict__ kth, ushort* __restrict__ ktm, ushort* __restrict__ ktl,
    ushort* __restrict__ vth, ushort* __restrict__ vtm, ushort* __restrict__ vtl)
{
    int isv = blockIdx.x;
    int tbh = blockIdx.y;
    int tb = tbh >> 3, h = tbh & 7;
    const ushort* src = (isv ? vsp : ksp) + (long)tb*PLANE + h*HDD;

    __shared__ ushort Ws[3][48][72];

    int tid = threadIdx.x, lane = tid & 63, w = tid >> 6;
    int q4 = lane >> 4, l16 = lane & 15;

    for (int idx = tid; idx < 1728; idx += 256) {
        int pl = idx / 576, rem = idx % 576;
        int e = rem / 12, cu = rem % 12;
        *(unsigned*)&Ws[pl][e][48 + cu*2] = 0;
    }
    for (int idx = tid; idx < 2304; idx += 256) {
        int e = idx / 48, d = idx % 48;
        float v = dw[idx];
        ushort hi = f2bf(v);  float r1 = v - bf2f(hi);
        ushort md = f2bf(r1); float r2 = r1 - bf2f(md);
        ushort lo = f2bf(r2);
        Ws[0][e][d] = hi; Ws[1][e][d] = md; Ws[2][e][d] = lo;
    }
    __syncthreads();

    f32x4 acc[3][4];
    #pragma unroll
    for (int es = 0; es < 3; es++)
        #pragma unroll
        for (int nt = 0; nt < 4; nt++) acc[es][nt] = (f32x4){0.f,0.f,0.f,0.f};

    #pragma unroll
    for (int k0 = 0; k0 < 64; k0 += 32) {
        short8 a[3][3];
        #pragma unroll
        for (int pl = 0; pl < 3; pl++)
            #pragma unroll
            for (int es = 0; es < 3; es++)
                a[pl][es] = *(short8*)&Ws[pl][es*16 + l16][k0 + q4*8];
        #pragma unroll
        for (int nt = 0; nt < 4; nt++) {
            int n = w*64 + nt*16 + l16;
            short8 xr = *(const short8*)(src + (long)n*CC + k0 + q4*8);
            #pragma unroll
            for (int es = 0; es < 3; es++) {
                acc[es][nt] = __builtin_amdgcn_mfma_f32_16x16x32_bf16(a[0][es], xr, acc[es][nt], 0, 0, 0);
                acc[es][nt] = __builtin_amdgcn_mfma_f32_16x16x32_bf16(a[1][es], xr, acc[es][nt], 0, 0, 0);
                acc[es][nt] = __builtin_amdgcn_mfma_f32_16x16x32_bf16(a[2][es], xr, acc[es][nt], 0, 0, 0);
            }
        }
    }

    #pragma unroll
    for (int es = 0; es < 3; es++) {
        #pragma unroll
        for (int r = 0; r < 4; r++) {
            int e = es*16 + q4*4 + r;
            float g = dbn[e], be = dbn[48+e], mu = dbn[96+e], va = dbn[144+e];
            float inv = g / sqrtf(va + 1e-5f);
            #pragma unroll
            for (int nt = 0; nt < 4; nt++) {
                int n = w*64 + nt*16 + l16;
                float val = inv*(acc[es][nt][r] - mu) + be;
                ushort hi = f2bf(val);  float r1 = val - bf2f(hi);
                ushort md = f2bf(r1);   float r2 = r1 - bf2f(md);
                ushort lo = f2bf(r2);
                if (isv) {
                    long gi = ((long)tbh*HDD + e)*NS + n;
                    vth[gi] = hi; vtm[gi] = md; vtl[gi] = lo;
                } else {
                    long gi = ((long)tbh*NS + n)*HDD + e;
                    kth[gi] = hi; ktm[gi] = md; ktl[gi] = lo;
                }
            }
        }
    }
}

// ---------------- MFMA attention: QK^T * c1 -> fused LIF(0.5) -> u8 map ----------------
__global__ __launch_bounds__(256) void k_attn_mfma(
    const ushort* __restrict__ qtim,
    const ushort* __restrict__ kth, const ushort* __restrict__ ktm, const ushort* __restrict__ ktl,
    const unsigned* __restrict__ cnt, unsigned char* __restrict__ amap)
{
    int bh = blockIdx.z;
    int b = bh >> 3, h = bh & 7;
    int nbase = blockIdx.y*64, mbase = blockIdx.x*64;

    __shared__ ushort Qs[64][72];
    __shared__ ushort Kh[64][72];
    __shared__ ushort Km[64][72];
    __shared__ ushort Kl[64][72];

    int tid  = threadIdx.x;
    int lane = tid & 63, w = tid >> 6;
    int q4 = lane >> 4, l16 = lane & 15;

    float mean = (float)(*cnt) / 6291456.0f;
    float c1 = fminf(1.0f / sqrtf(mean*48.0f + 1e-6f), 10.0f);

    {
        unsigned* z0 = (unsigned*)&Qs[0][0];
        unsigned* z1 = (unsigned*)&Kh[0][0];
        unsigned* z2 = (unsigned*)&Km[0][0];
        unsigned* z3 = (unsigned*)&Kl[0][0];
        for (int i2 = tid; i2 < 64*72/2; i2 += 256) {
            z0[i2] = 0; z1[i2] = 0; z2[i2] = 0; z3[i2] = 0;
        }
    }

    float vmem[4][4];
    #pragma unroll
    for (int a = 0; a < 4; a++)
        #pragma unroll
        for (int r = 0; r < 4; r++) vmem[a][r] = 0.f;

    for (int t = 0; t < TT; t++) {
        int tb = t*BB + b;
        __syncthreads();
        const ushort* qsrc = qtim + (long)tb*PLANE + (long)nbase*CC + h*HDD;
        for (int idx = tid; idx < 768; idx += 256) {
            int n = idx / 12, c4 = idx % 12;
            *(uint2*)&Qs[n][c4*4] = *(const uint2*)(qsrc + (long)n*CC + c4*4);
        }
        long kb0 = ((long)(tb*NHD + h)*NS + mbase)*HDD;
        const ushort* kbh = kth + kb0;
        const ushort* kbm = ktm + kb0;
        const ushort* kbl = ktl + kb0;
        for (int idx = tid; idx < 1536; idx += 256) {
            int e2 = idx << 1;
            int m = e2 / HDD, er = e2 % HDD;
            *(unsigned*)&Kh[m][er] = *(const unsigned*)(kbh + e2);
            *(unsigned*)&Km[m][er] = *(const unsigned*)(kbm + e2);
            *(unsigned*)&Kl[m][er] = *(const unsigned*)(kbl + e2);
        }
        __syncthreads();

        int nrow = w*16 + l16;
        f32x4 acc[4];
        #pragma unroll
        for (int mt = 0; mt < 4; mt++) acc[mt] = (f32x4){0.f, 0.f, 0.f, 0.f};

        #pragma unroll
        for (int ks = 0; ks < 2; ks++) {
            short8 a = *(short8*)&Qs[nrow][ks*32 + q4*8];
            #pragma unroll
            for (int mt = 0; mt < 4; mt++) {
                int mrow = mt*16 + l16;
                short8 b_h = *(short8*)&Kh[mrow][ks*32 + q4*8];
                short8 b_m = *(short8*)&Km[mrow][ks*32 + q4*8];
                short8 b_l = *(short8*)&Kl[mrow][ks*32 + q4*8];
                acc[mt] = __builtin_amdgcn_mfma_f32_16x16x32_bf16(a, b_h, acc[mt], 0, 0, 0);
                acc[mt] = __builtin_amdgcn_mfma_f32_16x16x32_bf16(a, b_m, acc[mt], 0, 0, 0);
                acc[mt] = __builtin_amdgcn_mfma_f32_16x16x32_bf16(a, b_l, acc[mt], 0, 0, 0);
            }
        }

        long abase0 = ((long)(tb*NHD + h)*NS)*NS;
        #pragma unroll
        for (int mt = 0; mt < 4; mt++) {
            int m = mbase + mt*16 + l16;
            #pragma unroll
            for (int r = 0; r < 4; r++) {
                int n = nbase + w*16 + q4*4 + r;
                float a = acc[mt][r]*c1;
                float v = vmem[mt][r];
                v += (a - v)*0.5f;
                float s = (v - 0.5f) >= 0.f ? 1.f : 0.f;
                amap[abase0 + (long)n*NS + m] = (unsigned char)s;
                vmem[mt][r] = v*(1.f - s);
            }
        }
    }
}

// ---------------- MFMA out = amap @ v_t + identity -> oid fp32 [tb][c][n] ----------------
__global__ __launch_bounds__(512) void k_outmm_mfma(
    const unsigned char* __restrict__ amap,
    const ushort* __restrict__ vth, const ushort* __restrict__ vtm, const ushort* __restrict__ vtl,
    const float* __restrict__ x, float* __restrict__ oid)
{
    int tbh = blockIdx.x;
    int tb = tbh >> 3, h = tbh & 7;
    int tid = threadIdx.x, lane = tid & 63, w = tid >> 6;
    int q4 = lane >> 4, l16 = lane & 15;
    int nbase = w*32;

    long vbase = (long)tbh*HDD*NS;

    f32x4 acc[2][3];
    #pragma unroll
    for (int nt = 0; nt < 2; nt++)
        #pragma unroll
        for (int et = 0; et < 3; et++) acc[nt][et] = (f32x4){0.f,0.f,0.f,0.f};

    for (int k0 = 0; k0 < NS; k0 += 32) {
        short8 a[2];
        #pragma unroll
        for (int nt = 0; nt < 2; nt++) {
            const unsigned char* arow = amap + ((long)tbh*NS + nbase + nt*16 + l16)*NS;
            uint2 u = *(const uint2*)(arow + k0 + q4*8);
            #pragma unroll
            for (int j = 0; j < 4; j++) {
                a[nt][j]   = ((u.x >> (8*j)) & 0xFFu) ? (short)0x3F80 : (short)0;
                a[nt][j+4] = ((u.y >> (8*j)) & 0xFFu) ? (short)0x3F80 : (short)0;
            }
        }
        #pragma unroll
        for (int et = 0; et < 3; et++) {
            long vo = vbase + (long)(et*16 + l16)*NS + k0 + q4*8;
            short8 bh = *(const short8*)(vth + vo);
            short8 bm = *(const short8*)(vtm + vo);
            short8 bl = *(const short8*)(vtl + vo);
            #pragma unroll
            for (int nt = 0; nt < 2; nt++) {
                acc[nt][et] = __builtin_amdgcn_mfma_f32_16x16x32_bf16(a[nt], bh, acc[nt][et], 0, 0, 0);
                acc[nt][et] = __builtin_amdgcn_mfma_f32_16x16x32_bf16(a[nt], bm, acc[nt][et], 0, 0, 0);
                acc[nt][et] = __builtin_amdgcn_mfma_f32_16x16x32_bf16(a[nt], bl, acc[nt][et], 0, 0, 0);
            }
        }
    }
    #pragma unroll
    for (int nt = 0; nt < 2; nt++) {
        #pragma unroll
        for (int et = 0; et < 3; et++) {
            int e = et*16 + l16;
            int n = nbase + nt*16 + q4*4;
            long base = (long)tb*PLANE + (long)(h*HDD + e)*NS + n;
            float4 xi = *(const float4*)(x + base);
            float4 o4;
            o4.x = acc[nt][et][0] + xi.x;
            o4.y = acc[nt][et][1] + xi.y;
            o4.z = acc[nt][et][2] + xi.z;
            o4.w = acc[nt][et][3] + xi.w;
            *(float4*)(oid + base) = o4;
        }
    }
}

// ---------------- proj GEMM + bias + BN (fp32, LDS) ----------------
__global__ __launch_bounds__(256) void k_gemm_proj(
    const float* __restrict__ W, const float* __restrict__ bias, const float* __restrict__ bn,
    const float* __restrict__ Xfull, float* __restrict__ Yfull)
{
    int tb = blockIdx.z;
    const float* X = Xfull + (long)tb*PLANE;
    float* Y = Yfull + (long)tb*PLANE;
    int d0 = blockIdx.y*64, n0 = blockIdx.x*64;

    __shared__ float As[16][68];
    __shared__ float Bs[16][68];
    int tid = threadIdx.x;
    int ty = tid >> 4, tx = tid & 15;
    float acc[4][4] = {};

    for (int k0 = 0; k0 < CC; k0 += 16) {
        {
            int d = tid >> 2, kq = (tid & 3)*4;
            float4 a4 = *(const float4*)&W[(long)(d0+d)*CC + k0 + kq];
            As[kq+0][d]=a4.x; As[kq+1][d]=a4.y; As[kq+2][d]=a4.z; As[kq+3][d]=a4.w;
        }
        {
            int k = tid >> 4, nq = (tid & 15)*4;
            *(float4*)&Bs[k][nq] = *(const float4*)&X[(long)(k0+k)*NS + n0 + nq];
        }
        __syncthreads();
        #pragma unroll
        for (int kk = 0; kk < 16; kk++) {
            float a0=As[kk][ty*4+0], a1=As[kk][ty*4+1], a2=As[kk][ty*4+2], a3=As[kk][ty*4+3];
            float b0=Bs[kk][tx*4+0], b1=Bs[kk][tx*4+1], b2=Bs[kk][tx*4+2], b3=Bs[kk][tx*4+3];
            acc[0][0]+=a0*b0; acc[0][1]+=a0*b1; acc[0][2]+=a0*b2; acc[0][3]+=a0*b3;
            acc[1][0]+=a1*b0; acc[1][1]+=a1*b1; acc[1][2]+=a1*b2; acc[1][3]+=a1*b3;
            acc[2][0]+=a2*b0; acc[2][1]+=a2*b1; acc[2][2]+=a2*b2; acc[2][3]+=a2*b3;
            acc[3][0]+=a3*b0; acc[3][1]+=a3*b1; acc[3][2]+=a3*b2; acc[3][3]+=a3*b3;
        }
        __syncthreads();
    }
    #pragma unroll
    for (int i = 0; i < 4; i++) {
        int d = d0 + ty*4 + i;
        float g = bn[d], be = bn[CC+d], mu = bn[2*CC+d], va = bn[3*CC+d];
        float inv = g / sqrtf(va + 1e-5f);
        float bv = bias[d];
        float4 o4;
        o4.x = inv*((acc[i][0]+bv) - mu) + be;
        o4.y = inv*((acc[i][1]+bv) - mu) + be;
        o4.z = inv*((acc[i][2]+bv) - mu) + be;
        o4.w = inv*((acc[i][3]+bv) - mu) + be;
        *(float4*)&Y[(long)d*NS + n0 + tx*4] = o4;
    }
}

// ---------------- final LIF (vth=1.0) -> d_out ----------------
__global__ __launch_bounds__(256) void k_final_lif(const float* __restrict__ pre,
                                                   float* __restrict__ out)
{
    int i = blockIdx.x*256 + threadIdx.x;
    float v = 0.f;
    #pragma unroll
    for (int t = 0; t < TT; t++) {
        float xt = pre[t*TSTR + i];
        v += (xt - v)*0.5f;
        float s = (v - 1.0f) >= 0.f ? 1.f : 0.f;
        out[t*TSTR + i] = s;
        v *= (1.f - s);
    }
}

extern "C" void kernel_launch(void* const* d_in, const int* in_sizes, int n_in,
                              void* d_out, int out_size, void* d_ws, size_t ws_size,
                              hipStream_t stream) {
    const float* x   = (const float*)d_in[0];
    const float* wq  = (const float*)d_in[1];
    const float* wk  = (const float*)d_in[2];
    const float* wv  = (const float*)d_in[3];
    const float* kbn = (const float*)d_in[4];
    const float* vbn = (const float*)d_in[5];
    const float* dw  = (const float*)d_in[6];
    const float* dbn = (const float*)d_in[7];
    const float* pw  = (const float*)d_in[8];
    const float* pb  = (const float*)d_in[9];
    const float* pbn = (const float*)d_in[10];
    const float* tw  = (const float*)d_in[11];
    const float* tbi = (const float*)d_in[12];

    float* out  = (float*)d_out;
    float* vout = out + TOT;

    float* ws   = (float*)d_ws;
    ushort* xs  = (ushort*)(ws + OFF_XS);
    float* oid  = ws + OFF_XS;
    float* qb   = ws + OFF_Q;      // q_pre fp32 (dead after step 3)
    float* cq   = ws + OFF_Q;      // Cq[2] fp32 (steps 4a-4c; overlaid by qtim at step 5)
    float* kb   = ws + OFF_K;
    float* vb   = ws + OFF_V;
    ushort* qtim = (ushort*)(ws + OFF_Q);          // Q lower half (step 5+)
    ushort* vtl  = (ushort*)(ws + OFF_Q) + TOT;    // Q upper half (step 6-8)
    ushort* qspT = (ushort*)(ws + OFF_OUTS);
    ushort* splT = qspT + 4L*PPL;
    ushort* ksp  = qspT + 7L*PPL;
    unsigned char* amap = (unsigned char*)(ws + OFF_OUTS);
    ushort* vsp = (ushort*)d_out;
    unsigned* partials = (unsigned*)(ws + OFF_KTS);
    ushort* wsp  = (ushort*)(ws + OFF_KTS) + 32768;
    ushort* timw = wsp + 9L*CCSQ;
    ushort* kth = (ushort*)(ws + OFF_KTS);
    ushort* ktm = kth + TOT;
    ushort* ktl = kth + 2L*TOT;
    ushort* vth = (ushort*)(ws + OFF_VT);
    ushort* vtm = vth + TOT;
    unsigned* cnt = (unsigned*)(ws + OFF_CNT);

    // 1. transpose-LIF -> xs [t][b][n][c]; split weights (tim fragment-major); zero pads
    k_lif_x_t<<<dim3(4, 6, 16), 256, 0, stream>>>(x, xs);
    k_wsplit<<<dim3(3*CCSQ/256), 256, 0, stream>>>(wq, wk, wv, wsp);
    k_wsplit_tim<<<dim3(CCSQ/256), 256, 0, stream>>>(tw, timw);
    k_zero_pads<<<dim3(336), 256, 0, stream>>>((unsigned*)qspT);
    // 2. q/k/v 1x1 convs via MFMA; all outputs n-major (+BN for k,v)
    k_gemm_qkv_mfma<<<dim3(6, 192), 512, 0, stream>>>(wsp, kbn, vbn, xs, qb, kb, vb);
    // 3. LIF: q->qspT padded; k->ksp u16; v->vsp u16 + vout
    k_lif_qkv<<<dim3(TSTR/256, 3), 256, 0, stream>>>(qb, kb, vb, qspT, ksp, vsp, vout);
    // 4a. batched conv(q_t) t=0,1,2, n-tile 128: t=0 -> s_1 spikes; t=1,2 -> Cq fp32
    k_tim_convq_mfma<<<dim3(2, 6, 48), 512, 0, stream>>>(timw, tbi, qspT, splT, cq);
    // 4b/4c. serial s-conv steps (768 blocks each)
    for (int i = 2; i <= 3; i++) {
        k_tim_convs_mfma<<<dim3(4, 12, 16), 256, 0, stream>>>(
            timw, tbi,
            splT + (long)(i-2)*PPL,
            cq + (long)(i-2)*TSTR,
            splT + (long)(i-1)*PPL);
    }
    // 5. TIM output LIF -> qtim bf16 spikes + per-block counts
    k_tim_lif<<<dim3(NPART), 256, 0, stream>>>(qspT, splT, qtim, partials);
    k_cnt_reduce<<<dim3(1), 256, 0, stream>>>(partials, cnt);
    // 6. MFMA dst transform + bn_last
    k_dst_mfma<<<dim3(2, 512), 256, 0, stream>>>(dw, dbn, ksp, vsp, kth, ktm, ktl, vth, vtm, vtl);
    // 7. MFMA attention + fused LIF -> binary map
    k_attn_mfma<<<dim3(4, 4, 128), 256, 0, stream>>>(qtim, kth, ktm, ktl, cnt, amap);
    // 8. MFMA out = amap @ v_t + identity -> oid fp32
    k_outmm_mfma<<<dim3(512), 512, 0, stream>>>(amap, vth, vtm, vtl, x, oid);
    // 9. proj GEMM + bias + BN (fp32 LDS; proj_pre into kb buffer)
    k_gemm_proj<<<dim3(4, 6, 64), 256, 0, stream>>>(pw, pb, pbn, oid, kb);
    // 10. final LIF -> out
    k_final_lif<<<dim3(TSTR/256), 256, 0, stream>>>(kb, out);
}

// Round 19
// 562.046 us; speedup vs baseline: 1.3875x; 1.0697x over previous
//
#include <hip/hip_runtime.h>
#include <math.h>

#define TT 4
#define BB 16
#define CC 384
#define NS 256
#define NHD 8
#define HDD 48
#define PLANE 98304      /* CC*NS */
#define TSTR  1572864    /* BB*PLANE */
#define TOT   6291456    /* TT*TSTR */
#define CCSQ  147456     /* CC*CC */
#define PB    99840      /* padded batch plane: 260*384 u16 */
#define PPL   1597440    /* padded t-plane: 16*260*384 u16 */
#define WCHK  12288      /* CC*32: one fragment-major W chunk (u16) */

// workspace float offsets (total (8*TOT+16)*4 = 201.3 MB)
#define OFF_XS   0L
#define OFF_Q    (1L*TOT)
#define OFF_K    (2L*TOT)
#define OFF_V    (3L*TOT)
#define OFF_OUTS (4L*TOT)
#define OFF_KTS  (11L*TOT/2)
#define OFF_VT   (7L*TOT)
#define OFF_CNT  (8L*TOT)

#define NPART 6144

typedef __attribute__((ext_vector_type(8))) short short8;
typedef __attribute__((ext_vector_type(4))) float f32x4;

__device__ __forceinline__ ushort f2bf(float x) {   // RTNE fp32->bf16
    union { float f; unsigned u; } c; c.f = x;
    unsigned r = c.u + 0x7FFFu + ((c.u >> 16) & 1u);
    return (ushort)(r >> 16);
}
__device__ __forceinline__ float bf2f(ushort h) {
    union { unsigned u; float f; } c; c.u = ((unsigned)h) << 16;
    return c.f;
}

// ---------------- fused transpose + LIF: x [t][b][c][n] -> xs [t][b][n][c] bf16 spikes ----------------
__global__ __launch_bounds__(256) void k_lif_x_t(const float* __restrict__ x,
                                                 ushort* __restrict__ xs)
{
    int b = blockIdx.z, c0 = blockIdx.y*64, n0 = blockIdx.x*64;
    __shared__ ushort T[64][72];
    int tid = threadIdx.x;
    int row = tid >> 2;
    int col4 = tid & 3;

    float v[16];
    #pragma unroll
    for (int i = 0; i < 16; i++) v[i] = 0.f;

    for (int t = 0; t < TT; t++) {
        __syncthreads();
        #pragma unroll
        for (int rep = 0; rep < 4; rep++) {
            int j = col4 + rep*4;
            float4 xv = *(const float4*)&x[(long)t*TSTR + (long)b*PLANE + (long)(c0+row)*NS + n0 + j*4];
            #pragma unroll
            for (int jj = 0; jj < 4; jj++) {
                int idx = rep*4 + jj;
                float xt = ((const float*)&xv)[jj];
                float vv = v[idx];
                vv += (xt - vv)*0.5f;
                float s = (vv - 1.0f) >= 0.f ? 1.f : 0.f;
                T[j*4+jj][row] = (s != 0.f) ? (ushort)0x3F80 : (ushort)0;
                v[idx] = vv*(1.f - s);
            }
        }
        __syncthreads();
        #pragma unroll
        for (int rep = 0; rep < 2; rep++) {
            int nrow = tid >> 2;
            int cq = (tid & 3) + rep*4;
            *(uint4*)&xs[(long)t*TSTR + (long)b*PLANE + (long)(n0+nrow)*CC + c0 + cq*8]
                = *(uint4*)&T[nrow][cq*8];
        }
    }
}

// ---------------- zero the halo pad rows of qspT (4 t) and splT (3 planes) ----------------
__global__ __launch_bounds__(256) void k_zero_pads(unsigned* __restrict__ qspT_u32)
{
    int i = blockIdx.x*256 + threadIdx.x;
    int plane = i / 768, rem = i % 768;
    int r = rem / 192, cu = rem % 192;
    int row = (r < 2) ? r : (256 + r);
    qspT_u32[(long)plane*(PB/2) + row*192 + cu] = 0;
}

// ---------------- split wq/wk/wv into bf16 hi/mid/lo planes ----------------
__global__ __launch_bounds__(256) void k_wsplit(
    const float* __restrict__ wq, const float* __restrict__ wk, const float* __restrict__ wv,
    ushort* __restrict__ wsp)
{
    int i = blockIdx.x*256 + threadIdx.x;
    int which = i / CCSQ, r = i % CCSQ;
    const float* W = (which==0) ? wq : (which==1 ? wk : wv);
    float v = W[r];
    ushort hi = f2bf(v);  float r1 = v - bf2f(hi);
    ushort md = f2bf(r1); float r2 = r1 - bf2f(md);
    ushort lo = f2bf(r2);
    long b = (long)which*3*CCSQ;
    wsp[b + r] = hi; wsp[b + CCSQ + r] = md; wsp[b + 2L*CCSQ + r] = lo;
}

// ---------------- split tim conv weights, FRAGMENT-MAJOR: timwP[pt][chunk][d][c32] ----------------
__global__ __launch_bounds__(256) void k_wsplit_tim(const float* __restrict__ tw,
                                                    ushort* __restrict__ timw)
{
    int i = blockIdx.x*256 + threadIdx.x;   // [0, CCSQ) = (d,c), d-major
    int d = i / CC, c = i % CC;
    int ch = c >> 5, cw = c & 31;
    const float* src = tw + (long)i*5;
    #pragma unroll
    for (int tap = 0; tap < 5; tap++) {
        float v = src[tap];
        ushort hi = f2bf(v);  float r1 = v - bf2f(hi);
        ushort md = f2bf(r1); float r2 = r1 - bf2f(md);
        ushort lo = f2bf(r2);
        long o = (long)d*32 + cw;
        timw[((long)(0*5 + tap)*12 + ch)*WCHK + o] = hi;
        timw[((long)(1*5 + tap)*12 + ch)*WCHK + o] = md;
        timw[((long)(2*5 + tap)*12 + ch)*WCHK + o] = lo;
    }
}

// ---------------- MFMA QKV GEMM v4: all outputs n-major [b][n][c] fp32 ----------------
__global__ __launch_bounds__(512) void k_gemm_qkv_mfma(
    const ushort* __restrict__ wsp,
    const float* __restrict__ kbn, const float* __restrict__ vbn,
    const ushort* __restrict__ xs,
    float* __restrict__ qo, float* __restrict__ ko, float* __restrict__ vo)
{
    int which = blockIdx.y >> 6;      // 0=q,1=k,2=v
    int tb    = blockIdx.y & 63;
    const ushort* X = xs + (long)tb*PLANE;
    const ushort* Wb = wsp + (long)which*3*CCSQ;
    int d0 = blockIdx.x*64;

    __shared__ ushort Ws[3][64][40];
    __shared__ ushort Xs[256][40];

    int tid = threadIdx.x, lane = tid & 63, w = tid >> 6;
    int q4 = lane >> 4, l16 = lane & 15;
    int dstrip = w & 3, nh = w >> 2;

    f32x4 acc[8];
    #pragma unroll
    for (int nt = 0; nt < 8; nt++) acc[nt] = (f32x4){0.f,0.f,0.f,0.f};

    for (int k0 = 0; k0 < CC; k0 += 32) {
        __syncthreads();
        for (int idx = tid; idx < 1792; idx += 512) {
            if (idx < 768) {
                int pl = idx >> 8, rem = idx & 255;
                int d = rem >> 2, c8 = rem & 3;
                *(uint4*)&Ws[pl][d][c8*8] =
                    *(const uint4*)(Wb + (long)pl*CCSQ + (long)(d0+d)*CC + k0 + c8*8);
            } else {
                int j = idx - 768;
                int n = j >> 2, c8 = j & 3;
                *(uint4*)&Xs[n][c8*8] = *(const uint4*)(X + (long)n*CC + k0 + c8*8);
            }
        }
        __syncthreads();

        short8 wh = *(short8*)&Ws[0][dstrip*16 + l16][q4*8];
        short8 wm = *(short8*)&Ws[1][dstrip*16 + l16][q4*8];
        short8 wl = *(short8*)&Ws[2][dstrip*16 + l16][q4*8];
        #pragma unroll
        for (int nt = 0; nt < 8; nt++) {
            short8 xr = *(short8*)&Xs[nh*128 + nt*16 + l16][q4*8];
            acc[nt] = __builtin_amdgcn_mfma_f32_16x16x32_bf16(xr, wh, acc[nt], 0, 0, 0);
            acc[nt] = __builtin_amdgcn_mfma_f32_16x16x32_bf16(xr, wm, acc[nt], 0, 0, 0);
            acc[nt] = __builtin_amdgcn_mfma_f32_16x16x32_bf16(xr, wl, acc[nt], 0, 0, 0);
        }
    }

    float* Y = ((which==0) ? qo : (which==1 ? ko : vo)) + (long)tb*PLANE;
    int d = d0 + dstrip*16 + l16;
    float inv = 1.f, mu = 0.f, be = 0.f;
    if (which != 0) {
        const float* bn = (which==1) ? kbn : vbn;
        float g = bn[d]; be = bn[CC+d]; mu = bn[2*CC+d]; float va = bn[3*CC+d];
        inv = g / sqrtf(va + 1e-5f);
    }
    #pragma unroll
    for (int nt = 0; nt < 8; nt++) {
        #pragma unroll
        for (int r = 0; r < 4; r++) {
            int n = nh*128 + nt*16 + q4*4 + r;
            float v = acc[nt][r];
            if (which != 0) v = inv*(v - mu) + be;
            Y[(long)n*CC + d] = v;
        }
    }
}

// ---------------- LIF: q->qspT padded bf16; k->ksp u16; v->vsp u16 + vout fp32 ----------------
__global__ __launch_bounds__(256) void k_lif_qkv(
    const float* __restrict__ qb, const float* __restrict__ kb, const float* __restrict__ vb,
    ushort* __restrict__ qspT, ushort* __restrict__ ksp, ushort* __restrict__ vsp,
    float* __restrict__ vout)
{
    int which = blockIdx.y;
    int i = blockIdx.x*256 + threadIdx.x;   // flat [b][n][c]
    const float* rbuf = (which==0) ? qb : (which==1 ? kb : vb);
    float vth  = (which==0) ? 0.05f : 1.0f;
    int b = i / PLANE;
    long qofs = (long)i + b*1536 + 768;     // padded [b][n+2][c] (q only)
    int c=0, n2=0, h=0, dd=0;
    if (which == 2) {
        c = i % CC; n2 = (i / CC) % NS;
        h = c / HDD; dd = c % HDD;
    }
    float v = 0.f;
    #pragma unroll
    for (int t = 0; t < TT; t++) {
        float xt = rbuf[t*TSTR + i];
        v += (xt - v)*0.5f;
        float s = (v - vth) >= 0.f ? 1.f : 0.f;
        ushort sb = (s != 0.f) ? (ushort)0x3F80 : (ushort)0;
        if (which == 0)      qspT[(long)t*PPL + qofs] = sb;
        else if (which == 1) ksp[(long)t*TSTR + i] = sb;
        else {
            vsp[(long)t*TSTR + i] = sb;
            vout[(((long)(t*BB+b)*NHD + h)*NS + n2)*HDD + dd] = s;
        }
        v *= (1.f - s);
    }
}

// ---------------- batched MFMA conv(q_t), t=0,1,2 — n-tile 128 for W reuse ----------------
__global__ __launch_bounds__(512) void k_tim_convq_mfma(
    const ushort* __restrict__ timw, const float* __restrict__ bias,
    const ushort* __restrict__ qspT,    // padded planes [t][16][260][384]
    ushort* __restrict__ s1out,         // splT plane 0 (padded)
    float* __restrict__ cq)             // [2][b][n][c] fp32
{
    int z = blockIdx.z;                 // t*16 + b
    int t = z >> 4, b = z & 15;
    int d0 = blockIdx.y*64, n0 = blockIdx.x*128;
    const ushort* qp = qspT + (long)t*PPL + (long)b*PB;

    __shared__ ushort Xs[132][40];      // halo rows; 10.6 KB

    int tid = threadIdx.x, lane = tid & 63, w = tid >> 6;   // 8 waves
    int q4 = lane >> 4, l16 = lane & 15;
    int dstrip = w & 3, nh = w >> 2;    // wave: 16 d x 64 n

    const ushort* wbase = timw + (long)(d0 + dstrip*16 + l16)*32 + q4*8;

    f32x4 accQ[4];
    #pragma unroll
    for (int nt = 0; nt < 4; nt++) accQ[nt] = (f32x4){0.f,0.f,0.f,0.f};

    for (int c0 = 0; c0 < CC; c0 += 32) {
        int ch = c0 >> 5;
        __syncthreads();
        for (int idx = tid; idx < 528; idx += 512) {    // 132 rows x 4 uint4
            int r = idx >> 2, c8 = idx & 3;
            *(uint4*)&Xs[r][c8*8] = *(const uint4*)(qp + (long)(n0 + r)*CC + c0 + c8*8);
        }
        __syncthreads();

        #pragma unroll
        for (int tap = 0; tap < 5; tap++) {
            short8 w0 = *(const short8*)(wbase + ((long)(0*5 + tap)*12 + ch)*WCHK);
            short8 w1 = *(const short8*)(wbase + ((long)(1*5 + tap)*12 + ch)*WCHK);
            short8 w2 = *(const short8*)(wbase + ((long)(2*5 + tap)*12 + ch)*WCHK);
            #pragma unroll
            for (int nt = 0; nt < 4; nt++) {
                int row = nh*64 + nt*16 + l16 + tap;
                short8 aq = *(short8*)&Xs[row][q4*8];
                accQ[nt] = __builtin_amdgcn_mfma_f32_16x16x32_bf16(aq, w0, accQ[nt], 0, 0, 0);
                accQ[nt] = __builtin_amdgcn_mfma_f32_16x16x32_bf16(aq, w1, accQ[nt], 0, 0, 0);
                accQ[nt] = __builtin_amdgcn_mfma_f32_16x16x32_bf16(aq, w2, accQ[nt], 0, 0, 0);
            }
        }
    }

    int d = d0 + dstrip*16 + l16;
    if (t == 0) {
        ushort* so = s1out + (long)b*PB;
        float bv = bias[d];
        #pragma unroll
        for (int nt = 0; nt < 4; nt++) {
            #pragma unroll
            for (int r = 0; r < 4; r++) {
                int n = n0 + nh*64 + nt*16 + q4*4 + r;
                float c = accQ[nt][r] + bv;
                float s = (c*0.5f - 0.3f) >= 0.f ? 1.f : 0.f;
                so[(long)(n + 2)*CC + d] = (s != 0.f) ? (ushort)0x3F80 : (ushort)0;
            }
        }
    } else {
        float* co = cq + (long)(t-1)*TSTR + (long)b*PLANE;
        #pragma unroll
        for (int nt = 0; nt < 4; nt++) {
            #pragma unroll
            for (int r = 0; r < 4; r++) {
                int n = n0 + nh*64 + nt*16 + q4*4 + r;
                co[(long)n*CC + d] = accQ[nt][r];
            }
        }
    }
}

// ---------------- serial MFMA conv(s_{i-1}) + combine with Cq (fragment-major W) ----------------
__global__ __launch_bounds__(256) void k_tim_convs_mfma(
    const ushort* __restrict__ timw, const float* __restrict__ bias,
    const ushort* __restrict__ sTp,     // s_{i-1} padded plane
    const float* __restrict__ cq,       // conv(q_{i-1}) fp32 [b][n][c]
    ushort* __restrict__ sTo)           // s_i padded plane
{
    int b = blockIdx.z, d0 = blockIdx.y*32, n0 = blockIdx.x*64;
    const ushort* sp = sTp + (long)b*PB;

    __shared__ ushort Xs[68][40];

    int tid = threadIdx.x, lane = tid & 63, w = tid >> 6;   // 4 waves
    int q4 = lane >> 4, l16 = lane & 15;
    int dstrip = w >> 1, nh = w & 1;

    const ushort* wbase = timw + (long)(d0 + dstrip*16 + l16)*32 + q4*8;

    f32x4 accS[2];
    accS[0] = (f32x4){0.f,0.f,0.f,0.f};
    accS[1] = (f32x4){0.f,0.f,0.f,0.f};

    for (int c0 = 0; c0 < CC; c0 += 32) {
        int ch = c0 >> 5;
        __syncthreads();
        for (int idx = tid; idx < 272; idx += 256) {
            int r = idx >> 2, c8 = idx & 3;
            *(uint4*)&Xs[r][c8*8] = *(const uint4*)(sp + (long)(n0 + r)*CC + c0 + c8*8);
        }
        __syncthreads();

        #pragma unroll
        for (int tap = 0; tap < 5; tap++) {
            short8 w0 = *(const short8*)(wbase + ((long)(0*5 + tap)*12 + ch)*WCHK);
            short8 w1 = *(const short8*)(wbase + ((long)(1*5 + tap)*12 + ch)*WCHK);
            short8 w2 = *(const short8*)(wbase + ((long)(2*5 + tap)*12 + ch)*WCHK);
            #pragma unroll
            for (int nt = 0; nt < 2; nt++) {
                int row = nh*32 + nt*16 + l16 + tap;
                short8 as = *(short8*)&Xs[row][q4*8];
                accS[nt] = __builtin_amdgcn_mfma_f32_16x16x32_bf16(as, w0, accS[nt], 0, 0, 0);
                accS[nt] = __builtin_amdgcn_mfma_f32_16x16x32_bf16(as, w1, accS[nt], 0, 0, 0);
                accS[nt] = __builtin_amdgcn_mfma_f32_16x16x32_bf16(as, w2, accS[nt], 0, 0, 0);
            }
        }
    }

    ushort* so = sTo + (long)b*PB;
    const float* co = cq + (long)b*PLANE;
    int d = d0 + dstrip*16 + l16;
    float bv = bias[d];
    #pragma unroll
    for (int nt = 0; nt < 2; nt++) {
        #pragma unroll
        for (int r = 0; r < 4; r++) {
            int n = n0 + nh*32 + nt*16 + q4*4 + r;
            float conv = 0.6f*accS[nt][r] + 0.4f*co[(long)n*CC + d];
            float c = conv + bv;
            float s = (c*0.5f - 0.3f) >= 0.f ? 1.f : 0.f;
            so[(long)(n + 2)*CC + d] = (s != 0.f) ? (ushort)0x3F80 : (ushort)0;
        }
    }
}

// ---------------- TIM output LIF -> qtim [b][n][c] + counts ----------------
__global__ __launch_bounds__(256) void k_tim_lif(const ushort* __restrict__ qspT,
                                                 const ushort* __restrict__ splT,
                                                 ushort* __restrict__ qtim,
                                                 unsigned* __restrict__ partials)
{
    int i = blockIdx.x*256 + threadIdx.x;
    int b = i / PLANE;
    long po = (long)i + b*1536 + 768;
    float v = 0.f; unsigned c = 0;
    #pragma unroll
    for (int t = 0; t < TT; t++) {
        float val;
        if (t == 0) {
            val = bf2f(qspT[po]);
        } else {
            float sf = bf2f(splT[(long)(t-1)*PPL + po]);
            float qf = bf2f(qspT[(long)t*PPL + po]);
            val = sf*0.6f + qf*0.4f;
        }
        v += (val - v)*0.5f;
        float s = (v - 0.5f) >= 0.f ? 1.f : 0.f;
        qtim[(long)t*TSTR + i] = (s != 0.f) ? (ushort)0x3F80 : (ushort)0;
        c += (unsigned)s;
        v *= (1.f - s);
    }
    #pragma unroll
    for (int off = 32; off >= 1; off >>= 1) c += __shfl_down(c, off, 64);
    __shared__ unsigned wsum[4];
    if ((threadIdx.x & 63) == 0) wsum[threadIdx.x >> 6] = c;
    __syncthreads();
    if (threadIdx.x == 0)
        partials[blockIdx.x] = wsum[0] + wsum[1] + wsum[2] + wsum[3];
}

// ---------------- reduce NPART partials -> cnt ----------------
__global__ __launch_bounds__(256) void k_cnt_reduce(const unsigned* __restrict__ partials,
                                                    unsigned* __restrict__ cnt)
{
    unsigned c = 0;
    for (int i = threadIdx.x; i < NPART; i += 256) c += partials[i];
    #pragma unroll
    for (int off = 32; off >= 1; off >>= 1) c += __shfl_down(c, off, 64);
    __shared__ unsigned wsum[4];
    if ((threadIdx.x & 63) == 0) wsum[threadIdx.x >> 6] = c;
    __syncthreads();
    if (threadIdx.x == 0)
        cnt[0] = wsum[0] + wsum[1] + wsum[2] + wsum[3];
}

// ---------------- MFMA dst transform + bn_last ----------------
// k-side now computes D[n][e] (operand-swapped MFMA) so kt[n][e] stores are
// lane-contiguous in e (R17: 2-B stores at 96-B stride -> 233 MB write-RMW).
__global__ __launch_bounds__(256) void k_dst_mfma(
    const float* __restrict__ dw, const float* __restrict__ dbn,
    const ushort* __restrict__ ksp, const ushort* __restrict__ vsp,
    ushort* __restrict__ kth, ushort* __restrict__ ktm, ushort* __restrict__ ktl,
    ushort* __restrict__ vth, ushort* __restrict__ vtm, ushort* __restrict__ vtl)
{
    int isv = blockIdx.x;
    int tbh = blockIdx.y;
    int tb = tbh >> 3, h = tbh & 7;
    const ushort* src = (isv ? vsp : ksp) + (long)tb*PLANE + h*HDD;

    __shared__ ushort Ws[3][48][72];

    int tid = threadIdx.x, lane = tid & 63, w = tid >> 6;
    int q4 = lane >> 4, l16 = lane & 15;

    for (int idx = tid; idx < 1728; idx += 256) {
        int pl = idx / 576, rem = idx % 576;
        int e = rem / 12, cu = rem % 12;
        *(unsigned*)&Ws[pl][e][48 + cu*2] = 0;
    }
    for (int idx = tid; idx < 2304; idx += 256) {
        int e = idx / 48, d = idx % 48;
        float v = dw[idx];
        ushort hi = f2bf(v);  float r1 = v - bf2f(hi);
        ushort md = f2bf(r1); float r2 = r1 - bf2f(md);
        ushort lo = f2bf(r2);
        Ws[0][e][d] = hi; Ws[1][e][d] = md; Ws[2][e][d] = lo;
    }
    __syncthreads();

    f32x4 acc[3][4];
    #pragma unroll
    for (int es = 0; es < 3; es++)
        #pragma unroll
        for (int nt = 0; nt < 4; nt++) acc[es][nt] = (f32x4){0.f,0.f,0.f,0.f};

    #pragma unroll
    for (int k0 = 0; k0 < 64; k0 += 32) {
        short8 a[3][3];
        #pragma unroll
        for (int pl = 0; pl < 3; pl++)
            #pragma unroll
            for (int es = 0; es < 3; es++)
                a[pl][es] = *(short8*)&Ws[pl][es*16 + l16][k0 + q4*8];
        #pragma unroll
        for (int nt = 0; nt < 4; nt++) {
            int n = w*64 + nt*16 + l16;
            short8 xr = *(const short8*)(src + (long)n*CC + k0 + q4*8);
            #pragma unroll
            for (int es = 0; es < 3; es++) {
                if (isv) {  // D[e][n]: rows e, cols n (vt [e][n] store contiguous in n)
                    acc[es][nt] = __builtin_amdgcn_mfma_f32_16x16x32_bf16(a[0][es], xr, acc[es][nt], 0, 0, 0);
                    acc[es][nt] = __builtin_amdgcn_mfma_f32_16x16x32_bf16(a[1][es], xr, acc[es][nt], 0, 0, 0);
                    acc[es][nt] = __builtin_amdgcn_mfma_f32_16x16x32_bf16(a[2][es], xr, acc[es][nt], 0, 0, 0);
                } else {    // D[n][e]: rows n, cols e (kt [n][e] store contiguous in e)
                    acc[es][nt] = __builtin_amdgcn_mfma_f32_16x16x32_bf16(xr, a[0][es], acc[es][nt], 0, 0, 0);
                    acc[es][nt] = __builtin_amdgcn_mfma_f32_16x16x32_bf16(xr, a[1][es], acc[es][nt], 0, 0, 0);
                    acc[es][nt] = __builtin_amdgcn_mfma_f32_16x16x32_bf16(xr, a[2][es], acc[es][nt], 0, 0, 0);
                }
            }
        }
    }

    if (isv) {
        #pragma unroll
        for (int es = 0; es < 3; es++) {
            #pragma unroll
            for (int r = 0; r < 4; r++) {
                int e = es*16 + q4*4 + r;
                float g = dbn[e], be = dbn[48+e], mu = dbn[96+e], va = dbn[144+e];
                float inv = g / sqrtf(va + 1e-5f);
                #pragma unroll
                for (int nt = 0; nt < 4; nt++) {
                    int n = w*64 + nt*16 + l16;
                    float val = inv*(acc[es][nt][r] - mu) + be;
                    ushort hi = f2bf(val);  float r1 = val - bf2f(hi);
                    ushort md = f2bf(r1);   float r2 = r1 - bf2f(md);
                    ushort lo = f2bf(r2);
                    long gi = ((long)tbh*HDD + e)*NS + n;
                    vth[gi] = hi; vtm[gi] = md; vtl[gi] = lo;
                }
            }
        }
    } else {
        #pragma unroll
        for (int es = 0; es < 3; es++) {
            int e = es*16 + l16;
            float g = dbn[e], be = dbn[48+e], mu = dbn[96+e], va = dbn[144+e];
            float inv = g / sqrtf(va + 1e-5f);
            #pragma unroll
            for (int nt = 0; nt < 4; nt++) {
                #pragma unroll
                for (int r = 0; r < 4; r++) {
                    int n = w*64 + nt*16 + q4*4 + r;
                    float val = inv*(acc[es][nt][r] - mu) + be;
                    ushort hi = f2bf(val);  float r1 = val - bf2f(hi);
                    ushort md = f2bf(r1);   float r2 = r1 - bf2f(md);
                    ushort lo = f2bf(r2);
                    long gi = ((long)tbh*NS + n)*HDD + e;
                    kth[gi] = hi; ktm[gi] = md; ktl[gi] = lo;
                }
            }
        }
    }
}

// ---------------- MFMA attention: QK^T * c1 -> fused LIF(0.5) -> u8 map ----------------
__global__ __launch_bounds__(256) void k_attn_mfma(
    const ushort* __restrict__ qtim,
    const ushort* __restrict__ kth, const ushort* __restrict__ ktm, const ushort* __restrict__ ktl,
    const unsigned* __restrict__ cnt, unsigned char* __restrict__ amap)
{
    int bh = blockIdx.z;
    int b = bh >> 3, h = bh & 7;
    int nbase = blockIdx.y*64, mbase = blockIdx.x*64;

    __shared__ ushort Qs[64][72];
    __shared__ ushort Kh[64][72];
    __shared__ ushort Km[64][72];
    __shared__ ushort Kl[64][72];

    int tid  = threadIdx.x;
    int lane = tid & 63, w = tid >> 6;
    int q4 = lane >> 4, l16 = lane & 15;

    float mean = (float)(*cnt) / 6291456.0f;
    float c1 = fminf(1.0f / sqrtf(mean*48.0f + 1e-6f), 10.0f);

    {
        unsigned* z0 = (unsigned*)&Qs[0][0];
        unsigned* z1 = (unsigned*)&Kh[0][0];
        unsigned* z2 = (unsigned*)&Km[0][0];
        unsigned* z3 = (unsigned*)&Kl[0][0];
        for (int i2 = tid; i2 < 64*72/2; i2 += 256) {
            z0[i2] = 0; z1[i2] = 0; z2[i2] = 0; z3[i2] = 0;
        }
    }

    float vmem[4][4];
    #pragma unroll
    for (int a = 0; a < 4; a++)
        #pragma unroll
        for (int r = 0; r < 4; r++) vmem[a][r] = 0.f;

    for (int t = 0; t < TT; t++) {
        int tb = t*BB + b;
        __syncthreads();
        const ushort* qsrc = qtim + (long)tb*PLANE + (long)nbase*CC + h*HDD;
        for (int idx = tid; idx < 768; idx += 256) {
            int n = idx / 12, c4 = idx % 12;
            *(uint2*)&Qs[n][c4*4] = *(const uint2*)(qsrc + (long)n*CC + c4*4);
        }
        long kb0 = ((long)(tb*NHD + h)*NS + mbase)*HDD;
        const ushort* kbh = kth + kb0;
        const ushort* kbm = ktm + kb0;
        const ushort* kbl = ktl + kb0;
        for (int idx = tid; idx < 1536; idx += 256) {
            int e2 = idx << 1;
            int m = e2 / HDD, er = e2 % HDD;
            *(unsigned*)&Kh[m][er] = *(const unsigned*)(kbh + e2);
            *(unsigned*)&Km[m][er] = *(const unsigned*)(kbm + e2);
            *(unsigned*)&Kl[m][er] = *(const unsigned*)(kbl + e2);
        }
        __syncthreads();

        int nrow = w*16 + l16;
        f32x4 acc[4];
        #pragma unroll
        for (int mt = 0; mt < 4; mt++) acc[mt] = (f32x4){0.f, 0.f, 0.f, 0.f};

        #pragma unroll
        for (int ks = 0; ks < 2; ks++) {
            short8 a = *(short8*)&Qs[nrow][ks*32 + q4*8];
            #pragma unroll
            for (int mt = 0; mt < 4; mt++) {
                int mrow = mt*16 + l16;
                short8 b_h = *(short8*)&Kh[mrow][ks*32 + q4*8];
                short8 b_m = *(short8*)&Km[mrow][ks*32 + q4*8];
                short8 b_l = *(short8*)&Kl[mrow][ks*32 + q4*8];
                acc[mt] = __builtin_amdgcn_mfma_f32_16x16x32_bf16(a, b_h, acc[mt], 0, 0, 0);
                acc[mt] = __builtin_amdgcn_mfma_f32_16x16x32_bf16(a, b_m, acc[mt], 0, 0, 0);
                acc[mt] = __builtin_amdgcn_mfma_f32_16x16x32_bf16(a, b_l, acc[mt], 0, 0, 0);
            }
        }

        long abase0 = ((long)(tb*NHD + h)*NS)*NS;
        #pragma unroll
        for (int mt = 0; mt < 4; mt++) {
            int m = mbase + mt*16 + l16;
            #pragma unroll
            for (int r = 0; r < 4; r++) {
                int n = nbase + w*16 + q4*4 + r;
                float a = acc[mt][r]*c1;
                float v = vmem[mt][r];
                v += (a - v)*0.5f;
                float s = (v - 0.5f) >= 0.f ? 1.f : 0.f;
                amap[abase0 + (long)n*NS + m] = (unsigned char)s;
                vmem[mt][r] = v*(1.f - s);
            }
        }
    }
}

// ---------------- MFMA out = amap @ v_t + identity -> oid fp32 [tb][c][n] ----------------
__global__ __launch_bounds__(512) void k_outmm_mfma(
    const unsigned char* __restrict__ amap,
    const ushort* __restrict__ vth, const ushort* __restrict__ vtm, const ushort* __restrict__ vtl,
    const float* __restrict__ x, float* __restrict__ oid)
{
    int tbh = blockIdx.x;
    int tb = tbh >> 3, h = tbh & 7;
    int tid = threadIdx.x, lane = tid & 63, w = tid >> 6;
    int q4 = lane >> 4, l16 = lane & 15;
    int nbase = w*32;

    long vbase = (long)tbh*HDD*NS;

    f32x4 acc[2][3];
    #pragma unroll
    for (int nt = 0; nt < 2; nt++)
        #pragma unroll
        for (int et = 0; et < 3; et++) acc[nt][et] = (f32x4){0.f,0.f,0.f,0.f};

    for (int k0 = 0; k0 < NS; k0 += 32) {
        short8 a[2];
        #pragma unroll
        for (int nt = 0; nt < 2; nt++) {
            const unsigned char* arow = amap + ((long)tbh*NS + nbase + nt*16 + l16)*NS;
            uint2 u = *(const uint2*)(arow + k0 + q4*8);
            #pragma unroll
            for (int j = 0; j < 4; j++) {
                a[nt][j]   = ((u.x >> (8*j)) & 0xFFu) ? (short)0x3F80 : (short)0;
                a[nt][j+4] = ((u.y >> (8*j)) & 0xFFu) ? (short)0x3F80 : (short)0;
            }
        }
        #pragma unroll
        for (int et = 0; et < 3; et++) {
            long vo = vbase + (long)(et*16 + l16)*NS + k0 + q4*8;
            short8 bh = *(const short8*)(vth + vo);
            short8 bm = *(const short8*)(vtm + vo);
            short8 bl = *(const short8*)(vtl + vo);
            #pragma unroll
            for (int nt = 0; nt < 2; nt++) {
                acc[nt][et] = __builtin_amdgcn_mfma_f32_16x16x32_bf16(a[nt], bh, acc[nt][et], 0, 0, 0);
                acc[nt][et] = __builtin_amdgcn_mfma_f32_16x16x32_bf16(a[nt], bm, acc[nt][et], 0, 0, 0);
                acc[nt][et] = __builtin_amdgcn_mfma_f32_16x16x32_bf16(a[nt], bl, acc[nt][et], 0, 0, 0);
            }
        }
    }
    #pragma unroll
    for (int nt = 0; nt < 2; nt++) {
        #pragma unroll
        for (int et = 0; et < 3; et++) {
            int e = et*16 + l16;
            int n = nbase + nt*16 + q4*4;
            long base = (long)tb*PLANE + (long)(h*HDD + e)*NS + n;
            float4 xi = *(const float4*)(x + base);
            float4 o4;
            o4.x = acc[nt][et][0] + xi.x;
            o4.y = acc[nt][et][1] + xi.y;
            o4.z = acc[nt][et][2] + xi.z;
            o4.w = acc[nt][et][3] + xi.w;
            *(float4*)(oid + base) = o4;
        }
    }
}

// ---------------- proj GEMM + bias + BN (fp32, LDS) ----------------
__global__ __launch_bounds__(256) void k_gemm_proj(
    const float* __restrict__ W, const float* __restrict__ bias, const float* __restrict__ bn,
    const float* __restrict__ Xfull, float* __restrict__ Yfull)
{
    int tb = blockIdx.z;
    const float* X = Xfull + (long)tb*PLANE;
    float* Y = Yfull + (long)tb*PLANE;
    int d0 = blockIdx.y*64, n0 = blockIdx.x*64;

    __shared__ float As[16][68];
    __shared__ float Bs[16][68];
    int tid = threadIdx.x;
    int ty = tid >> 4, tx = tid & 15;
    float acc[4][4] = {};

    for (int k0 = 0; k0 < CC; k0 += 16) {
        {
            int d = tid >> 2, kq = (tid & 3)*4;
            float4 a4 = *(const float4*)&W[(long)(d0+d)*CC + k0 + kq];
            As[kq+0][d]=a4.x; As[kq+1][d]=a4.y; As[kq+2][d]=a4.z; As[kq+3][d]=a4.w;
        }
        {
            int k = tid >> 4, nq = (tid & 15)*4;
            *(float4*)&Bs[k][nq] = *(const float4*)&X[(long)(k0+k)*NS + n0 + nq];
        }
        __syncthreads();
        #pragma unroll
        for (int kk = 0; kk < 16; kk++) {
            float a0=As[kk][ty*4+0], a1=As[kk][ty*4+1], a2=As[kk][ty*4+2], a3=As[kk][ty*4+3];
            float b0=Bs[kk][tx*4+0], b1=Bs[kk][tx*4+1], b2=Bs[kk][tx*4+2], b3=Bs[kk][tx*4+3];
            acc[0][0]+=a0*b0; acc[0][1]+=a0*b1; acc[0][2]+=a0*b2; acc[0][3]+=a0*b3;
            acc[1][0]+=a1*b0; acc[1][1]+=a1*b1; acc[1][2]+=a1*b2; acc[1][3]+=a1*b3;
            acc[2][0]+=a2*b0; acc[2][1]+=a2*b1; acc[2][2]+=a2*b2; acc[2][3]+=a2*b3;
            acc[3][0]+=a3*b0; acc[3][1]+=a3*b1; acc[3][2]+=a3*b2; acc[3][3]+=a3*b3;
        }
        __syncthreads();
    }
    #pragma unroll
    for (int i = 0; i < 4; i++) {
        int d = d0 + ty*4 + i;
        float g = bn[d], be = bn[CC+d], mu = bn[2*CC+d], va = bn[3*CC+d];
        float inv = g / sqrtf(va + 1e-5f);
        float bv = bias[d];
        float4 o4;
        o4.x = inv*((acc[i][0]+bv) - mu) + be;
        o4.y = inv*((acc[i][1]+bv) - mu) + be;
        o4.z = inv*((acc[i][2]+bv) - mu) + be;
        o4.w = inv*((acc[i][3]+bv) - mu) + be;
        *(float4*)&Y[(long)d*NS + n0 + tx*4] = o4;
    }
}

// ---------------- final LIF (vth=1.0) -> d_out ----------------
__global__ __launch_bounds__(256) void k_final_lif(const float* __restrict__ pre,
                                                   float* __restrict__ out)
{
    int i = blockIdx.x*256 + threadIdx.x;
    float v = 0.f;
    #pragma unroll
    for (int t = 0; t < TT; t++) {
        float xt = pre[t*TSTR + i];
        v += (xt - v)*0.5f;
        float s = (v - 1.0f) >= 0.f ? 1.f : 0.f;
        out[t*TSTR + i] = s;
        v *= (1.f - s);
    }
}

extern "C" void kernel_launch(void* const* d_in, const int* in_sizes, int n_in,
                              void* d_out, int out_size, void* d_ws, size_t ws_size,
                              hipStream_t stream) {
    const float* x   = (const float*)d_in[0];
    const float* wq  = (const float*)d_in[1];
    const float* wk  = (const float*)d_in[2];
    const float* wv  = (const float*)d_in[3];
    const float* kbn = (const float*)d_in[4];
    const float* vbn = (const float*)d_in[5];
    const float* dw  = (const float*)d_in[6];
    const float* dbn = (const float*)d_in[7];
    const float* pw  = (const float*)d_in[8];
    const float* pb  = (const float*)d_in[9];
    const float* pbn = (const float*)d_in[10];
    const float* tw  = (const float*)d_in[11];
    const float* tbi = (const float*)d_in[12];

    float* out  = (float*)d_out;
    float* vout = out + TOT;

    float* ws   = (float*)d_ws;
    ushort* xs  = (ushort*)(ws + OFF_XS);
    float* oid  = ws + OFF_XS;
    float* qb   = ws + OFF_Q;
    float* cq   = ws + OFF_Q;
    float* kb   = ws + OFF_K;
    float* vb   = ws + OFF_V;
    ushort* qtim = (ushort*)(ws + OFF_Q);
    ushort* vtl  = (ushort*)(ws + OFF_Q) + TOT;
    ushort* qspT = (ushort*)(ws + OFF_OUTS);
    ushort* splT = qspT + 4L*PPL;
    ushort* ksp  = qspT + 7L*PPL;
    unsigned char* amap = (unsigned char*)(ws + OFF_OUTS);
    ushort* vsp = (ushort*)d_out;
    unsigned* partials = (unsigned*)(ws + OFF_KTS);
    ushort* wsp  = (ushort*)(ws + OFF_KTS) + 32768;
    ushort* timw = wsp + 9L*CCSQ;
    ushort* kth = (ushort*)(ws + OFF_KTS);
    ushort* ktm = kth + TOT;
    ushort* ktl = kth + 2L*TOT;
    ushort* vth = (ushort*)(ws + OFF_VT);
    ushort* vtm = vth + TOT;
    unsigned* cnt = (unsigned*)(ws + OFF_CNT);

    // 1. transpose-LIF -> xs [t][b][n][c]; split weights; zero pads
    k_lif_x_t<<<dim3(4, 6, 16), 256, 0, stream>>>(x, xs);
    k_wsplit<<<dim3(3*CCSQ/256), 256, 0, stream>>>(wq, wk, wv, wsp);
    k_wsplit_tim<<<dim3(CCSQ/256), 256, 0, stream>>>(tw, timw);
    k_zero_pads<<<dim3(336), 256, 0, stream>>>((unsigned*)qspT);
    // 2. q/k/v 1x1 convs via MFMA; all outputs n-major (+BN for k,v)
    k_gemm_qkv_mfma<<<dim3(6, 192), 512, 0, stream>>>(wsp, kbn, vbn, xs, qb, kb, vb);
    // 3. LIF: q->qspT padded; k->ksp u16; v->vsp u16 + vout
    k_lif_qkv<<<dim3(TSTR/256, 3), 256, 0, stream>>>(qb, kb, vb, qspT, ksp, vsp, vout);
    // 4a. batched conv(q_t) t=0,1,2, n-tile 128
    k_tim_convq_mfma<<<dim3(2, 6, 48), 512, 0, stream>>>(timw, tbi, qspT, splT, cq);
    // 4b/4c. serial s-conv steps
    for (int i = 2; i <= 3; i++) {
        k_tim_convs_mfma<<<dim3(4, 12, 16), 256, 0, stream>>>(
            timw, tbi,
            splT + (long)(i-2)*PPL,
            cq + (long)(i-2)*TSTR,
            splT + (long)(i-1)*PPL);
    }
    // 5. TIM output LIF -> qtim bf16 spikes + counts
    k_tim_lif<<<dim3(NPART), 256, 0, stream>>>(qspT, splT, qtim, partials);
    k_cnt_reduce<<<dim3(1), 256, 0, stream>>>(partials, cnt);
    // 6. MFMA dst transform + bn_last (k-side D[n][e] for coalesced stores)
    k_dst_mfma<<<dim3(2, 512), 256, 0, stream>>>(dw, dbn, ksp, vsp, kth, ktm, ktl, vth, vtm, vtl);
    // 7. MFMA attention + fused LIF -> binary map
    k_attn_mfma<<<dim3(4, 4, 128), 256, 0, stream>>>(qtim, kth, ktm, ktl, cnt, amap);
    // 8. MFMA out = amap @ v_t + identity -> oid fp32
    k_outmm_mfma<<<dim3(512), 512, 0, stream>>>(amap, vth, vtm, vtl, x, oid);
    // 9. proj GEMM + bias + BN (fp32 LDS)
    k_gemm_proj<<<dim3(4, 6, 64), 256, 0, stream>>>(pw, pb, pbn, oid, kb);
    // 10. final LIF -> out
    k_final_lif<<<dim3(TSTR/256), 256, 0, stream>>>(kb, out);
}